// Round 9
// baseline (265.851 us; speedup 1.0000x reference)
//
#include <hip/hip_runtime.h>
#include <hip/hip_bf16.h>

#define B_ 4
#define L_ 2048
#define D_ 1024
#define F_ 4096
#define H_ 16
#define E_ 64

typedef __hip_bfloat16 bf16;
typedef __attribute__((ext_vector_type(8))) short short8;
typedef __attribute__((ext_vector_type(4))) float f32x4;
typedef __attribute__((ext_vector_type(16))) float f32x16;

__device__ __forceinline__ short f2bf(float f) {
    union { float f; unsigned u; } v;
    v.f = f;
    unsigned r = (v.u + 0x7fff + ((v.u >> 16) & 1)) >> 16;
    return (short)r;
}

// async global->LDS, 16B per lane, lands at ldsbase + lane*16
__device__ __forceinline__ void gl_lds16(const short* g, short* l) {
    __builtin_amdgcn_global_load_lds((const __attribute__((address_space(1))) void*)g,
                                     (__attribute__((address_space(3))) void*)l, 16, 0, 0);
}

// ---------------- fp32 -> bf16 convert ----------------
__global__ __launch_bounds__(256) void convert_bf16_kernel(const float* __restrict__ src,
                                                           bf16* __restrict__ dst, int n) {
    int i = (blockIdx.x * 256 + threadIdx.x) * 4;
    if (i + 3 < n) {
        float4 v = *(const float4*)(src + i);
        dst[i + 0] = __float2bfloat16(v.x);
        dst[i + 1] = __float2bfloat16(v.y);
        dst[i + 2] = __float2bfloat16(v.z);
        dst[i + 3] = __float2bfloat16(v.w);
    }
}

// ---------------- V^T pre-pass + bf16 x copy ----------------
__global__ __launch_bounds__(256) void transpose_vt_kernel(const float* __restrict__ x,
                                                           short* __restrict__ vt,
                                                           short* __restrict__ xb) {
    __shared__ float tile[64][65];
    const int bh = blockIdx.x, lt = blockIdx.y;
    const int b = bh >> 4, h = bh & 15;
    const int l0 = lt * 64;
    for (int idx = threadIdx.x; idx < 4096; idx += 256) {
        int r = idx >> 6, c = idx & 63;
        float v = x[((size_t)b * L_ + l0 + r) * D_ + h * E_ + c];
        tile[r][c] = v;
        xb[((size_t)b * L_ + l0 + r) * D_ + h * E_ + c] = f2bf(v);
    }
    __syncthreads();
    for (int idx = threadIdx.x; idx < 4096; idx += 256) {
        int e = idx >> 6, l = idx & 63;
        vt[((size_t)bh * E_ + e) * L_ + l0 + l] = f2bf(tile[l][e]);
    }
}

// ---------------- flash attention, swapped-operand 32x32 MFMA, in-register P ----------------
// grid 1024; XCD-grouping swizzle (id&7 owns 8 heads = 4MB K/V = its L2).
// K/V staged via global_load_lds into unpadded KV[2][2][64][64] with row-half-invariant
// XOR swizzle: phys chunk = logical ^ (r&7) (both-sides: pre-permuted stage source + read XOR).
// NOTE: (r&7) is identical for rows r and r+32, so ONE read base serves both row halves
// (the r7 diagonal variant broke exactly this invariant -> reverted).
// l-sum via ones-MFMA. Double-buffered, one __syncthreads per tile.
__global__ __launch_bounds__(256, 4) void flash_attn_kernel(const float* __restrict__ x,
                                                            const short* __restrict__ xb,
                                                            const short* __restrict__ vt,
                                                            float* __restrict__ attn_out) {
    __shared__ short KV[2][2][64][64];   // [buf][K=0/V=1][row][chunk*8]

    const int tid = threadIdx.x;
    const int w = tid >> 6, lane = tid & 63;
    const int l31 = lane & 31;
    const int hi = lane >> 5;
    const int hi8 = hi * 8;

    // XCD-grouping bijection: blocks of one (b,h) stay on one XCD
    const int orig = blockIdx.x;
    const int xcd = orig & 7;
    const int seq = orig >> 3;
    const int qt = seq & 15;
    const int bh = ((seq >> 4) << 3) | xcd;
    const int b = bh >> 4, h = bh & 15;
    const int q0 = qt * 128;

    const short* kbase = xb + (size_t)b * L_ * D_ + h * E_;

    const float QS = 0.125f * 1.44269504f;
    const int qrow = q0 + w * 32 + l31;
    short8 qf[4];
    {
        const float* qp = x + ((size_t)b * L_ + qrow) * D_ + h * E_;
#pragma unroll
        for (int ks = 0; ks < 4; ks++) {
            float4 v0 = *(const float4*)(qp + ks * 16 + hi8);
            float4 v1 = *(const float4*)(qp + ks * 16 + hi8 + 4);
            short8 sc;
            sc[0] = f2bf(v0.x * QS); sc[1] = f2bf(v0.y * QS);
            sc[2] = f2bf(v0.z * QS); sc[3] = f2bf(v0.w * QS);
            sc[4] = f2bf(v1.x * QS); sc[5] = f2bf(v1.y * QS);
            sc[6] = f2bf(v1.z * QS); sc[7] = f2bf(v1.w * QS);
            qf[ks] = sc;
        }
    }

    // ones A-fragment for the l-sum MFMA (bf16 1.0 = 0x3F80)
    short8 ones;
#pragma unroll
    for (int z = 0; z < 8; z++) ones[z] = (short)0x3F80;

    f32x16 acc_o[2];
    f32x16 acc_l;
#pragma unroll
    for (int r = 0; r < 16; r++) { acc_o[0][r] = 0.f; acc_o[1][r] = 0.f; acc_l[r] = 0.f; }

    // staging: wave w covers rows [w*16, w*16+16) of K and of V; 4 issues/wave.
    // source chunk pre-permuted: phys chunk (lane&7) at row r holds logical (lane&7)^(r&7);
    // r&7 == srow for both 8-row issue groups.
    const int srow = lane >> 3;                       // 0..7 within 8-row issue
    const int schunk = ((lane & 7) ^ srow) * 8;       // logical chunk this lane fetches
    const short* ksrc0 = kbase + (size_t)(w * 16 + srow) * D_ + schunk;
    const short* vsrc0 = vt + ((size_t)bh * E_ + w * 16 + srow) * L_ + schunk;

#define STAGEF(bf_, t_)                                                     \
    do {                                                                    \
        const short* ks_ = ksrc0 + (size_t)(t_) * 64 * D_;                  \
        gl_lds16(ks_, &KV[bf_][0][w * 16][0]);                              \
        gl_lds16(ks_ + (size_t)8 * D_, &KV[bf_][0][w * 16 + 8][0]);         \
        const short* vs_ = vsrc0 + (size_t)(t_) * 64;                       \
        gl_lds16(vs_, &KV[bf_][1][w * 16][0]);                              \
        gl_lds16(vs_ + (size_t)8 * L_, &KV[bf_][1][w * 16 + 8][0]);         \
    } while (0)

    // per-lane read base: phys chunk of logical chunk (hi) at row l31; valid for rows
    // l31 and 32+l31 alike since the swizzle term is (r&7).
    const int p0 = l31 * 128 + ((((l31 & 7) ^ hi)) << 4);

    STAGEF(0, 0);   // prefetch tile 0

    const int NT = L_ / 64;
    for (int t = 0; t < NT; t++) {
        const int cur = t & 1;
        __syncthreads();   // drains vmcnt(0): tile t landed; all prior reads done

        if (t + 1 < NT) STAGEF(cur ^ 1, t + 1);   // covered by the compute below

        const char* kvb = (const char*)&KV[cur][0][0][0];

        f32x16 accp0, accp1;
#pragma unroll
        for (int r = 0; r < 16; r++) { accp0[r] = 0.f; accp1[r] = 0.f; }
        __builtin_amdgcn_s_setprio(1);
#pragma unroll
        for (int j = 0; j < 4; j++) {
            short8 kf0 = *(const short8*)(kvb + (p0 ^ (j << 5)));
            short8 kf1 = *(const short8*)(kvb + 4096 + (p0 ^ (j << 5)));
            accp0 = __builtin_amdgcn_mfma_f32_32x32x16_bf16(kf0, qf[j], accp0, 0, 0, 0);
            accp1 = __builtin_amdgcn_mfma_f32_32x32x16_bf16(kf1, qf[j], accp1, 0, 0, 0);
        }
        __builtin_amdgcn_s_setprio(0);

        float pe[2][16];
#pragma unroll
        for (int r = 0; r < 16; r++) {
            pe[0][r] = __builtin_amdgcn_exp2f(accp0[r]);
            pe[1][r] = __builtin_amdgcn_exp2f(accp1[r]);
        }

#pragma unroll
        for (int j = 0; j < 4; j++) {
            const int tt = j >> 1, o = (j & 1) * 8;
            unsigned X0, X1, Y0, Y1;
            asm("v_cvt_pk_bf16_f32 %0, %1, %2" : "=v"(X0) : "v"(pe[tt][o + 0]), "v"(pe[tt][o + 1]));
            asm("v_cvt_pk_bf16_f32 %0, %1, %2" : "=v"(X1) : "v"(pe[tt][o + 2]), "v"(pe[tt][o + 3]));
            asm("v_cvt_pk_bf16_f32 %0, %1, %2" : "=v"(Y0) : "v"(pe[tt][o + 4]), "v"(pe[tt][o + 5]));
            asm("v_cvt_pk_bf16_f32 %0, %1, %2" : "=v"(Y1) : "v"(pe[tt][o + 6]), "v"(pe[tt][o + 7]));
            asm("v_permlane32_swap_b32 %0, %1" : "+v"(X0), "+v"(Y0));
            asm("v_permlane32_swap_b32 %0, %1" : "+v"(X1), "+v"(Y1));
            int4 wi = make_int4((int)X0, (int)X1, (int)Y0, (int)Y1);
            short8 pb = *(short8*)&wi;

            __builtin_amdgcn_s_setprio(1);
            acc_l = __builtin_amdgcn_mfma_f32_32x32x16_bf16(ones, pb, acc_l, 0, 0, 0);
            short8 vf0 = *(const short8*)(kvb + 8192 + (p0 ^ (j << 5)));
            short8 vf1 = *(const short8*)(kvb + 12288 + (p0 ^ (j << 5)));
            acc_o[0] = __builtin_amdgcn_mfma_f32_32x32x16_bf16(vf0, pb, acc_o[0], 0, 0, 0);
            acc_o[1] = __builtin_amdgcn_mfma_f32_32x32x16_bf16(vf1, pb, acc_o[1], 0, 0, 0);
            __builtin_amdgcn_s_setprio(0);
        }
    }
#undef STAGEF

    // epilogue: O /= l (acc_l rows all identical = full l for column q)
    const float il = 1.0f / acc_l[0];
    float* op = attn_out + ((size_t)b * L_ + qrow) * D_ + h * E_ + hi * 4;
#pragma unroll
    for (int et = 0; et < 2; et++)
#pragma unroll
        for (int rg = 0; rg < 4; rg++) {
            float4 ov;
            ov.x = acc_o[et][rg * 4 + 0] * il;
            ov.y = acc_o[et][rg * 4 + 1] * il;
            ov.z = acc_o[et][rg * 4 + 2] * il;
            ov.w = acc_o[et][rg * 4 + 3] * il;
            *(float4*)(op + et * 32 + rg * 8) = ov;
        }
}

// ---------------- residual + layernorm (vectorized), optional second input ----------------
__global__ __launch_bounds__(256) void ln_kernel(const float* __restrict__ A,
                                                 const float* __restrict__ Bres,
                                                 const float* __restrict__ gamma,
                                                 const float* __restrict__ beta,
                                                 float* __restrict__ out_f32,
                                                 bf16* __restrict__ out_bf16) {
    __shared__ float reds[4], reds2[4];
    const int row = blockIdx.x, tid = threadIdx.x;
    const int c4 = tid * 4;
    float4 va = *(const float4*)(A + (size_t)row * D_ + c4);
    if (Bres) {
        float4 vb = *(const float4*)(Bres + (size_t)row * D_ + c4);
        va.x += vb.x; va.y += vb.y; va.z += vb.z; va.w += vb.w;
    }
    float s = va.x + va.y + va.z + va.w;
    float s2 = va.x * va.x + va.y * va.y + va.z * va.z + va.w * va.w;
#pragma unroll
    for (int o = 32; o > 0; o >>= 1) {
        s += __shfl_down(s, o, 64);
        s2 += __shfl_down(s2, o, 64);
    }
    if ((tid & 63) == 0) { reds[tid >> 6] = s; reds2[tid >> 6] = s2; }
    __syncthreads();
    s = reds[0] + reds[1] + reds[2] + reds[3];
    s2 = reds2[0] + reds2[1] + reds2[2] + reds2[3];
    float mean = s * (1.0f / D_);
    float var = s2 * (1.0f / D_) - mean * mean;
    float r = rsqrtf(var + 1e-5f);
    float4 vg = *(const float4*)(gamma + c4);
    float4 vbt = *(const float4*)(beta + c4);
    float4 o;
    o.x = (va.x - mean) * r * vg.x + vbt.x;
    o.y = (va.y - mean) * r * vg.y + vbt.y;
    o.z = (va.z - mean) * r * vg.z + vbt.z;
    o.w = (va.w - mean) * r * vg.w + vbt.w;
    if (out_f32) *(float4*)(out_f32 + (size_t)row * D_ + c4) = o;
    if (out_bf16) {
        unsigned p0 = ((unsigned)(unsigned short)f2bf(o.x)) | (((unsigned)(unsigned short)f2bf(o.y)) << 16);
        unsigned p1 = ((unsigned)(unsigned short)f2bf(o.z)) | (((unsigned)(unsigned short)f2bf(o.w)) << 16);
        int2 pk = make_int2((int)p0, (int)p1);
        *(int2*)((short*)out_bf16 + (size_t)row * D_ + c4) = pk;
    }
}

// ---------------- gemm1: 256x256 tile, BK=32, 8 waves 2Mx4N, 3-deep bufs, counted vmcnt ----------------
// T4 discipline (proven in gemm2_k): K-tile t in buf t%3, stage t+2 into buf (t+2)%3;
// vmcnt(4) at top (tile t+1's 4 issues stay in flight), ONE barrier per K-tile.
// 2 phases/K-tile: {read A i0-3 + B all, stage A(t+2), lgkm0, 16 MFMA} {read A i4-7, stage B(t+2), lgkm0, 16 MFMA}.
// T2 swizzle at BK=32: phys 16B chunk = quad ^ (row&3), both-sides.
__global__ __launch_bounds__(512, 1) void gemm1_k(const bf16* __restrict__ A,
                                                  const bf16* __restrict__ Bw,
                                                  const float* __restrict__ bias,
                                                  bf16* __restrict__ Cout,
                                                  int M, int N, int K) {
    __shared__ short As[3][256 * 32];
    __shared__ short Bs[3][256 * 32];

    const int tid = threadIdx.x;
    const int wid = tid >> 6, lane = tid & 63;
    const int wr = wid >> 2, wc = wid & 3;       // 2M x 4N waves, 128x64 out each
    const int lrow = lane & 15, quad = lane >> 4;

    // T1 bijective XCD swizzle (grid = 16 x 32 = 512 wg, %8==0)
    const int nbx = gridDim.x;
    const int id = blockIdx.y * nbx + blockIdx.x;
    const int chunk = (nbx * gridDim.y) >> 3;
    const int swz = (id & 7) * chunk + (id >> 3);
    const int bn = swz % nbx, bm = swz / nbx;

    // staging: each issue = 16-row group x 64B rows; lane covers row wid*16 + (lane>>2),
    // phys chunk lane&3; source chunk pre-permuted: (lane&3) ^ (row&3)
    const int srow = wid * 16 + (lane >> 2);
    const int scol = ((lane & 3) ^ ((lane >> 2) & 3)) * 8;
    const short* Ag = (const short*)A + (size_t)(bm * 256 + srow) * K + scol;
    const short* Bg = (const short*)Bw + (size_t)(bn * 256 + srow) * K + scol;

    f32x4 acc[8][4];
#pragma unroll
    for (int i = 0; i < 8; i++)
#pragma unroll
        for (int j = 0; j < 4; j++) acc[i][j] = (f32x4){0.f, 0.f, 0.f, 0.f};

#define STAGE1_A(dst, k0)                                                              \
    do {                                                                               \
        gl_lds16(Ag + (k0), (dst) + (wid * 16) * 32);                                  \
        gl_lds16(Ag + (size_t)128 * K + (k0), (dst) + (128 + wid * 16) * 32);          \
    } while (0)
#define STAGE1_B(dst, k0)                                                              \
    do {                                                                               \
        gl_lds16(Bg + (k0), (dst) + (wid * 16) * 32);                                  \
        gl_lds16(Bg + (size_t)128 * K + (k0), (dst) + (128 + wid * 16) * 32);          \
    } while (0)
#define RD1(base, R) (*(const short8*)&(base)[(R) * 32 + (((quad) ^ ((R) & 3)) * 8)])
#define LGKM0()                                            \
    do {                                                   \
        asm volatile("s_waitcnt lgkmcnt(0)" ::: "memory"); \
        __builtin_amdgcn_sched_barrier(0);                 \
    } while (0)

    short* a0 = &As[0][0];
    short* a1 = &As[1][0];
    short* a2 = &As[2][0];
    short* b0 = &Bs[0][0];
    short* b1 = &Bs[1][0];
    short* b2 = &Bs[2][0];

    // prologue: tiles 0 and 1 in flight (4 issues each, order A,A,B,B)
    STAGE1_A(a0, 0);
    STAGE1_B(b0, 0);
    STAGE1_A(a1, 32);
    STAGE1_B(b1, 32);

    const int NT = K / 32;
    for (int t = 0; t < NT; t++) {
        if (t < NT - 1)
            asm volatile("s_waitcnt vmcnt(4)" ::: "memory");   // tile t landed; t+1 in flight
        else
            asm volatile("s_waitcnt vmcnt(0)" ::: "memory");
        __builtin_amdgcn_s_barrier();
        __builtin_amdgcn_sched_barrier(0);
        const bool more = t + 2 < NT;
        const int kn = (t + 2) * 32;

        short8 af[4], bfr[4];
        // ---- ph0: A i0-3 + B all; stage A(t+2) ----
#pragma unroll
        for (int i = 0; i < 4; i++) af[i] = RD1(a0, wr * 128 + i * 16 + lrow);
#pragma unroll
        for (int j = 0; j < 4; j++) bfr[j] = RD1(b0, wc * 64 + j * 16 + lrow);
        if (more) STAGE1_A(a2, kn);
        LGKM0();
        __builtin_amdgcn_s_setprio(1);
#pragma unroll
        for (int i = 0; i < 4; i++)
#pragma unroll
            for (int j = 0; j < 4; j++)
                acc[i][j] = __builtin_amdgcn_mfma_f32_16x16x32_bf16(af[i], bfr[j], acc[i][j], 0, 0, 0);
        __builtin_amdgcn_s_setprio(0);

        // ---- ph1: A i4-7; stage B(t+2) ----
#pragma unroll
        for (int i = 0; i < 4; i++) af[i] = RD1(a0, wr * 128 + 64 + i * 16 + lrow);
        if (more) STAGE1_B(b2, kn);
        LGKM0();
        __builtin_amdgcn_s_setprio(1);
#pragma unroll
        for (int i = 0; i < 4; i++)
#pragma unroll
            for (int j = 0; j < 4; j++)
                acc[4 + i][j] = __builtin_amdgcn_mfma_f32_16x16x32_bf16(af[i], bfr[j], acc[4 + i][j], 0, 0, 0);
        __builtin_amdgcn_s_setprio(0);

        // rotate buffers
        short* ta = a0; a0 = a1; a1 = a2; a2 = ta;
        short* tb = b0; b0 = b1; b1 = b2; b2 = tb;
    }
#undef STAGE1_A
#undef STAGE1_B
#undef RD1
#undef LGKM0

    // epilogue: relu -> bf16
#pragma unroll
    for (int i = 0; i < 8; i++)
#pragma unroll
        for (int j = 0; j < 4; j++) {
            int col = bn * 256 + wc * 64 + j * 16 + lrow;
            float bv = bias[col];
#pragma unroll
            for (int r = 0; r < 4; r++) {
                int row = bm * 256 + wr * 128 + i * 16 + quad * 4 + r;
                float v = fmaxf(acc[i][j][r] + bv, 0.f);
                Cout[(size_t)row * N + col] = __float2bfloat16(v);
            }
        }
}

// ---------------- gemm2: 256x128 tile, 8 waves 4Mx2N, 3-deep buffers, counted vmcnt ----------------
__global__ __launch_bounds__(512, 1) void gemm2_k(const bf16* __restrict__ A,
                                                  const bf16* __restrict__ Bw,
                                                  const float* __restrict__ bias,
                                                  const float* __restrict__ RES,
                                                  float* __restrict__ Cout,
                                                  int M, int N, int K) {
    __shared__ short As[3][256 * 64];
    __shared__ short Bs[3][128 * 64];

    const int tid = threadIdx.x;
    const int wid = tid >> 6, lane = tid & 63;
    const int wr = wid >> 1, wc = wid & 1;       // 4M x 2N waves, 64x64 out each
    const int lrow = lane & 15, quad = lane >> 4;

    const int nbx = gridDim.x;
    const int id = blockIdx.y * nbx + blockIdx.x;
    const int chunk = (nbx * gridDim.y) >> 3;
    const int swz = (id & 7) * chunk + (id >> 3);
    const int bn = swz % nbx, bm = swz / nbx;

    const int srow = wid * 8 + (lane >> 3);
    const int scol = ((lane & 7) ^ ((lane >> 3) & 7)) * 8;   // pre-permuted source (T2, rule 21)
    const short* Ag = (const short*)A + (size_t)(bm * 256 + srow) * K + scol;
    const short* Bg = (const short*)Bw + (size_t)(bn * 128 + srow) * K + scol;

    f32x4 acc[4][4];
#pragma unroll
    for (int i = 0; i < 4; i++)
#pragma unroll
        for (int j = 0; j < 4; j++) acc[i][j] = (f32x4){0.f, 0.f, 0.f, 0.f};

#define STAGE2_A(dst, k0)                                                            \
    do {                                                                             \
        _Pragma("unroll") for (int s = 0; s < 4; s++)                                \
            gl_lds16(Ag + (size_t)s * 64 * K + (k0), (dst) + (s * 64 + wid * 8) * 64); \
    } while (0)
#define STAGE2_B(dst, k0)                                                            \
    do {                                                                             \
        _Pragma("unroll") for (int s = 0; s < 2; s++)                                \
            gl_lds16(Bg + (size_t)s * 64 * K + (k0), (dst) + (s * 64 + wid * 8) * 64); \
    } while (0)
#define RD2(base, R, q) (*(const short8*)&(base)[(R) * 64 + (((q) ^ ((R) & 7)) * 8)])
#define LGKM0()                                            \
    do {                                                   \
        asm volatile("s_waitcnt lgkmcnt(0)" ::: "memory"); \
        __builtin_amdgcn_sched_barrier(0);                 \
    } while (0)

    short* a0 = &As[0][0];
    short* a1 = &As[1][0];
    short* a2 = &As[2][0];
    short* b0 = &Bs[0][0];
    short* b1 = &Bs[1][0];
    short* b2 = &Bs[2][0];

    STAGE2_A(a0, 0);
    STAGE2_B(b0, 0);
    STAGE2_A(a1, 64);
    STAGE2_B(b1, 64);

    const int NT = K / 64;
    for (int t = 0; t < NT; t++) {
        if (t < NT - 1)
            asm volatile("s_waitcnt vmcnt(6)" ::: "memory");
        else
            asm volatile("s_waitcnt vmcnt(0)" ::: "memory");
        __builtin_amdgcn_s_barrier();
        __builtin_amdgcn_sched_barrier(0);
        const bool more = t + 2 < NT;
        const int kn = (t + 2) * 64;

        short8 afr[4][2], bfr[4][2];
#pragma unroll
        for (int i = 0; i < 4; i++)
#pragma unroll
            for (int kq = 0; kq < 2; kq++)
                afr[i][kq] = RD2(a0, wr * 64 + i * 16 + lrow, kq * 4 + quad);
#pragma unroll
        for (int j = 0; j < 2; j++)
#pragma unroll
            for (int kq = 0; kq < 2; kq++)
                bfr[j][kq] = RD2(b0, wc * 64 + j * 16 + lrow, kq * 4 + quad);
        if (more) STAGE2_A(a2, kn);
        LGKM0();
        __builtin_amdgcn_s_setprio(1);
#pragma unroll
        for (int i = 0; i < 4; i++)
#pragma unroll
            for (int j = 0; j < 2; j++)
#pragma unroll
                for (int kq = 0; kq < 2; kq++)
                    acc[i][j] = __builtin_amdgcn_mfma_f32_16x16x32_bf16(
                        afr[i][kq], bfr[j][kq], acc[i][j], 0, 0, 0);
        __builtin_amdgcn_s_setprio(0);

#pragma unroll
        for (int j = 2; j < 4; j++)
#pragma unroll
            for (int kq = 0; kq < 2; kq++)
                bfr[j][kq] = RD2(b0, wc * 64 + j * 16 + lrow, kq * 4 + quad);
        if (more) STAGE2_B(b2, kn);
        LGKM0();
        __builtin_amdgcn_s_setprio(1);
#pragma unroll
        for (int i = 0; i < 4; i++)
#pragma unroll
            for (int j = 2; j < 4; j++)
#pragma unroll
                for (int kq = 0; kq < 2; kq++)
                    acc[i][j] = __builtin_amdgcn_mfma_f32_16x16x32_bf16(
                        afr[i][kq], bfr[j][kq], acc[i][j], 0, 0, 0);
        __builtin_amdgcn_s_setprio(0);

        short* ta = a0; a0 = a1; a1 = a2; a2 = ta;
        short* tb = b0; b0 = b1; b1 = b2; b2 = tb;
    }
#undef STAGE2_A
#undef STAGE2_B
#undef RD2
#undef LGKM0

#pragma unroll
    for (int i = 0; i < 4; i++)
#pragma unroll
        for (int j = 0; j < 4; j++) {
            int col = bn * 128 + wc * 64 + j * 16 + lrow;
            float bv = bias[col];
#pragma unroll
            for (int r = 0; r < 4; r++) {
                int row = bm * 256 + wr * 64 + i * 16 + quad * 4 + r;
                float v = acc[i][j][r] + bv + RES[(size_t)row * N + col];
                Cout[(size_t)row * N + col] = v;
            }
        }
}

// ---------------- launch ----------------
extern "C" void kernel_launch(void* const* d_in, const int* in_sizes, int n_in,
                              void* d_out, int out_size, void* d_ws, size_t ws_size,
                              hipStream_t stream) {
    const float* x = (const float*)d_in[0];
    const float* w1 = (const float*)d_in[1];
    const float* b1 = (const float*)d_in[2];
    const float* w2 = (const float*)d_in[3];
    const float* b2 = (const float*)d_in[4];
    const float* g1 = (const float*)d_in[5];
    const float* be1 = (const float*)d_in[6];
    const float* g2 = (const float*)d_in[7];
    const float* be2 = (const float*)d_in[8];
    float* out = (float*)d_out;

    char* ws = (char*)d_ws;
    const size_t MB = 1024 * 1024;
    float* attn_out = (float*)(ws);            // 32 MiB
    float* x1 = (float*)(ws + 32 * MB);        // 32 MiB
    bf16* x1b = (bf16*)(ws + 64 * MB);         // 16 MiB
    bf16* w1b = (bf16*)(ws + 80 * MB);         // 8 MiB
    bf16* w2b = (bf16*)(ws + 88 * MB);         // 8 MiB
    bf16* hb = (bf16*)(ws + 96 * MB);          // 64 MiB (GEMM phase)
    // attention-phase buffers alias hb's region (dead once gemm1 runs):
    short* xb = (short*)(ws + 96 * MB);        // 16 MiB bf16 x
    short* vt = (short*)(ws + 112 * MB);       // 16 MiB bf16 x^T per (b,h)
    float* y2 = attn_out;                      // reuse

    convert_bf16_kernel<<<4096, 256, 0, stream>>>(w1, w1b, F_ * D_);
    convert_bf16_kernel<<<4096, 256, 0, stream>>>(w2, w2b, D_ * F_);
    transpose_vt_kernel<<<dim3(B_ * H_, L_ / 64), 256, 0, stream>>>(x, vt, xb);

    flash_attn_kernel<<<B_ * H_ * (L_ / 128), 256, 0, stream>>>(x, xb, vt, attn_out);

    ln_kernel<<<B_ * L_, 256, 0, stream>>>(x, attn_out, g1, be1, x1, x1b);

    // gemm1: M=8192, N=4096, K=1024 -> grid 16 x 32 = 512 wg, BK=32 counted pipeline
    gemm1_k<<<dim3(F_ / 256, (B_ * L_) / 256), 512, 0, stream>>>(
        x1b, w1b, b1, hb, B_ * L_, F_, D_);
    // gemm2: M=8192, N=1024, K=4096 -> grid 8 x 32 = 256 wg, 3-deep pipeline
    gemm2_k<<<dim3(D_ / 128, (B_ * L_) / 256), 512, 0, stream>>>(
        hb, w2b, b2, x1, y2, B_ * L_, D_, F_);

    ln_kernel<<<B_ * L_, 256, 0, stream>>>(y2, nullptr, g2, be2, out, nullptr);
}

// Round 10
// 263.994 us; speedup vs baseline: 1.0070x; 1.0070x over previous
//
#include <hip/hip_runtime.h>
#include <hip/hip_bf16.h>

#define B_ 4
#define L_ 2048
#define D_ 1024
#define F_ 4096
#define H_ 16
#define E_ 64

typedef __hip_bfloat16 bf16;
typedef __attribute__((ext_vector_type(8))) short short8;
typedef __attribute__((ext_vector_type(4))) float f32x4;
typedef __attribute__((ext_vector_type(16))) float f32x16;

__device__ __forceinline__ short f2bf(float f) {
    union { float f; unsigned u; } v;
    v.f = f;
    unsigned r = (v.u + 0x7fff + ((v.u >> 16) & 1)) >> 16;
    return (short)r;
}

// async global->LDS, 16B per lane, lands at ldsbase + lane*16
__device__ __forceinline__ void gl_lds16(const short* g, short* l) {
    __builtin_amdgcn_global_load_lds((const __attribute__((address_space(1))) void*)g,
                                     (__attribute__((address_space(3))) void*)l, 16, 0, 0);
}

// ---------------- fp32 -> bf16 convert ----------------
__global__ __launch_bounds__(256) void convert_bf16_kernel(const float* __restrict__ src,
                                                           bf16* __restrict__ dst, int n) {
    int i = (blockIdx.x * 256 + threadIdx.x) * 4;
    if (i + 3 < n) {
        float4 v = *(const float4*)(src + i);
        dst[i + 0] = __float2bfloat16(v.x);
        dst[i + 1] = __float2bfloat16(v.y);
        dst[i + 2] = __float2bfloat16(v.z);
        dst[i + 3] = __float2bfloat16(v.w);
    }
}

// ---------------- V^T pre-pass + bf16 x copy ----------------
__global__ __launch_bounds__(256) void transpose_vt_kernel(const float* __restrict__ x,
                                                           short* __restrict__ vt,
                                                           short* __restrict__ xb) {
    __shared__ float tile[64][65];
    const int bh = blockIdx.x, lt = blockIdx.y;
    const int b = bh >> 4, h = bh & 15;
    const int l0 = lt * 64;
    for (int idx = threadIdx.x; idx < 4096; idx += 256) {
        int r = idx >> 6, c = idx & 63;
        float v = x[((size_t)b * L_ + l0 + r) * D_ + h * E_ + c];
        tile[r][c] = v;
        xb[((size_t)b * L_ + l0 + r) * D_ + h * E_ + c] = f2bf(v);
    }
    __syncthreads();
    for (int idx = threadIdx.x; idx < 4096; idx += 256) {
        int e = idx >> 6, l = idx & 63;
        vt[((size_t)bh * E_ + e) * L_ + l0 + l] = f2bf(tile[l][e]);
    }
}

// ---------------- flash attention, swapped-operand 32x32 MFMA, in-register P ----------------
// grid 1024; XCD-grouping swizzle (id&7 owns 8 heads = 4MB K/V = its L2).
// K/V staged via global_load_lds into unpadded KV[2][2][64][64] with row-half-invariant
// XOR swizzle: phys chunk = logical ^ (r&7) (both-sides). The 8.4M "conflict" count on
// these reads is a counter artifact: 8 lanes per 4-bank group = 1KB/8cyc = b128 BW optimum.
// l-sum via ones-MFMA. Double-buffered, one __syncthreads per tile.
__global__ __launch_bounds__(256, 4) void flash_attn_kernel(const float* __restrict__ x,
                                                            const short* __restrict__ xb,
                                                            const short* __restrict__ vt,
                                                            float* __restrict__ attn_out) {
    __shared__ short KV[2][2][64][64];   // [buf][K=0/V=1][row][chunk*8]

    const int tid = threadIdx.x;
    const int w = tid >> 6, lane = tid & 63;
    const int l31 = lane & 31;
    const int hi = lane >> 5;
    const int hi8 = hi * 8;

    // XCD-grouping bijection: blocks of one (b,h) stay on one XCD
    const int orig = blockIdx.x;
    const int xcd = orig & 7;
    const int seq = orig >> 3;
    const int qt = seq & 15;
    const int bh = ((seq >> 4) << 3) | xcd;
    const int b = bh >> 4, h = bh & 15;
    const int q0 = qt * 128;

    const short* kbase = xb + (size_t)b * L_ * D_ + h * E_;

    const float QS = 0.125f * 1.44269504f;
    const int qrow = q0 + w * 32 + l31;
    short8 qf[4];
    {
        const float* qp = x + ((size_t)b * L_ + qrow) * D_ + h * E_;
#pragma unroll
        for (int ks = 0; ks < 4; ks++) {
            float4 v0 = *(const float4*)(qp + ks * 16 + hi8);
            float4 v1 = *(const float4*)(qp + ks * 16 + hi8 + 4);
            short8 sc;
            sc[0] = f2bf(v0.x * QS); sc[1] = f2bf(v0.y * QS);
            sc[2] = f2bf(v0.z * QS); sc[3] = f2bf(v0.w * QS);
            sc[4] = f2bf(v1.x * QS); sc[5] = f2bf(v1.y * QS);
            sc[6] = f2bf(v1.z * QS); sc[7] = f2bf(v1.w * QS);
            qf[ks] = sc;
        }
    }

    // ones A-fragment for the l-sum MFMA (bf16 1.0 = 0x3F80)
    short8 ones;
#pragma unroll
    for (int z = 0; z < 8; z++) ones[z] = (short)0x3F80;

    f32x16 acc_o[2];
    f32x16 acc_l;
#pragma unroll
    for (int r = 0; r < 16; r++) { acc_o[0][r] = 0.f; acc_o[1][r] = 0.f; acc_l[r] = 0.f; }

    // staging: wave w covers rows [w*16, w*16+16) of K and of V; 4 issues/wave.
    // source chunk pre-permuted: phys chunk (lane&7) at row r holds logical (lane&7)^(r&7).
    const int srow = lane >> 3;                       // 0..7 within 8-row issue
    const int schunk = ((lane & 7) ^ srow) * 8;       // logical chunk this lane fetches
    const short* ksrc0 = kbase + (size_t)(w * 16 + srow) * D_ + schunk;
    const short* vsrc0 = vt + ((size_t)bh * E_ + w * 16 + srow) * L_ + schunk;

#define STAGEF(bf_, t_)                                                     \
    do {                                                                    \
        const short* ks_ = ksrc0 + (size_t)(t_) * 64 * D_;                  \
        gl_lds16(ks_, &KV[bf_][0][w * 16][0]);                              \
        gl_lds16(ks_ + (size_t)8 * D_, &KV[bf_][0][w * 16 + 8][0]);         \
        const short* vs_ = vsrc0 + (size_t)(t_) * 64;                       \
        gl_lds16(vs_, &KV[bf_][1][w * 16][0]);                              \
        gl_lds16(vs_ + (size_t)8 * L_, &KV[bf_][1][w * 16 + 8][0]);         \
    } while (0)

    // per-lane read base: phys chunk of logical chunk (hi) at row l31; valid for rows
    // l31 and 32+l31 alike since the swizzle term is (r&7).
    const int p0 = l31 * 128 + ((((l31 & 7) ^ hi)) << 4);

    STAGEF(0, 0);   // prefetch tile 0

    const int NT = L_ / 64;
    for (int t = 0; t < NT; t++) {
        const int cur = t & 1;
        __syncthreads();   // drains vmcnt(0): tile t landed; all prior reads done

        if (t + 1 < NT) STAGEF(cur ^ 1, t + 1);   // covered by the compute below

        const char* kvb = (const char*)&KV[cur][0][0][0];

        f32x16 accp0, accp1;
#pragma unroll
        for (int r = 0; r < 16; r++) { accp0[r] = 0.f; accp1[r] = 0.f; }
        __builtin_amdgcn_s_setprio(1);
#pragma unroll
        for (int j = 0; j < 4; j++) {
            short8 kf0 = *(const short8*)(kvb + (p0 ^ (j << 5)));
            short8 kf1 = *(const short8*)(kvb + 4096 + (p0 ^ (j << 5)));
            accp0 = __builtin_amdgcn_mfma_f32_32x32x16_bf16(kf0, qf[j], accp0, 0, 0, 0);
            accp1 = __builtin_amdgcn_mfma_f32_32x32x16_bf16(kf1, qf[j], accp1, 0, 0, 0);
        }
        __builtin_amdgcn_s_setprio(0);

        float pe[2][16];
#pragma unroll
        for (int r = 0; r < 16; r++) {
            pe[0][r] = __builtin_amdgcn_exp2f(accp0[r]);
            pe[1][r] = __builtin_amdgcn_exp2f(accp1[r]);
        }

#pragma unroll
        for (int j = 0; j < 4; j++) {
            const int tt = j >> 1, o = (j & 1) * 8;
            unsigned X0, X1, Y0, Y1;
            asm("v_cvt_pk_bf16_f32 %0, %1, %2" : "=v"(X0) : "v"(pe[tt][o + 0]), "v"(pe[tt][o + 1]));
            asm("v_cvt_pk_bf16_f32 %0, %1, %2" : "=v"(X1) : "v"(pe[tt][o + 2]), "v"(pe[tt][o + 3]));
            asm("v_cvt_pk_bf16_f32 %0, %1, %2" : "=v"(Y0) : "v"(pe[tt][o + 4]), "v"(pe[tt][o + 5]));
            asm("v_cvt_pk_bf16_f32 %0, %1, %2" : "=v"(Y1) : "v"(pe[tt][o + 6]), "v"(pe[tt][o + 7]));
            asm("v_permlane32_swap_b32 %0, %1" : "+v"(X0), "+v"(Y0));
            asm("v_permlane32_swap_b32 %0, %1" : "+v"(X1), "+v"(Y1));
            int4 wi = make_int4((int)X0, (int)X1, (int)Y0, (int)Y1);
            short8 pb = *(short8*)&wi;

            __builtin_amdgcn_s_setprio(1);
            acc_l = __builtin_amdgcn_mfma_f32_32x32x16_bf16(ones, pb, acc_l, 0, 0, 0);
            short8 vf0 = *(const short8*)(kvb + 8192 + (p0 ^ (j << 5)));
            short8 vf1 = *(const short8*)(kvb + 12288 + (p0 ^ (j << 5)));
            acc_o[0] = __builtin_amdgcn_mfma_f32_32x32x16_bf16(vf0, pb, acc_o[0], 0, 0, 0);
            acc_o[1] = __builtin_amdgcn_mfma_f32_32x32x16_bf16(vf1, pb, acc_o[1], 0, 0, 0);
            __builtin_amdgcn_s_setprio(0);
        }
    }
#undef STAGEF

    // epilogue: O /= l (acc_l rows all identical = full l for column q)
    const float il = 1.0f / acc_l[0];
    float* op = attn_out + ((size_t)b * L_ + qrow) * D_ + h * E_ + hi * 4;
#pragma unroll
    for (int et = 0; et < 2; et++)
#pragma unroll
        for (int rg = 0; rg < 4; rg++) {
            float4 ov;
            ov.x = acc_o[et][rg * 4 + 0] * il;
            ov.y = acc_o[et][rg * 4 + 1] * il;
            ov.z = acc_o[et][rg * 4 + 2] * il;
            ov.w = acc_o[et][rg * 4 + 3] * il;
            *(float4*)(op + et * 32 + rg * 8) = ov;
        }
}

// ---------------- residual + layernorm (vectorized), optional second input ----------------
__global__ __launch_bounds__(256) void ln_kernel(const float* __restrict__ A,
                                                 const float* __restrict__ Bres,
                                                 const float* __restrict__ gamma,
                                                 const float* __restrict__ beta,
                                                 float* __restrict__ out_f32,
                                                 bf16* __restrict__ out_bf16) {
    __shared__ float reds[4], reds2[4];
    const int row = blockIdx.x, tid = threadIdx.x;
    const int c4 = tid * 4;
    float4 va = *(const float4*)(A + (size_t)row * D_ + c4);
    if (Bres) {
        float4 vb = *(const float4*)(Bres + (size_t)row * D_ + c4);
        va.x += vb.x; va.y += vb.y; va.z += vb.z; va.w += vb.w;
    }
    float s = va.x + va.y + va.z + va.w;
    float s2 = va.x * va.x + va.y * va.y + va.z * va.z + va.w * va.w;
#pragma unroll
    for (int o = 32; o > 0; o >>= 1) {
        s += __shfl_down(s, o, 64);
        s2 += __shfl_down(s2, o, 64);
    }
    if ((tid & 63) == 0) { reds[tid >> 6] = s; reds2[tid >> 6] = s2; }
    __syncthreads();
    s = reds[0] + reds[1] + reds[2] + reds[3];
    s2 = reds2[0] + reds2[1] + reds2[2] + reds2[3];
    float mean = s * (1.0f / D_);
    float var = s2 * (1.0f / D_) - mean * mean;
    float r = rsqrtf(var + 1e-5f);
    float4 vg = *(const float4*)(gamma + c4);
    float4 vbt = *(const float4*)(beta + c4);
    float4 o;
    o.x = (va.x - mean) * r * vg.x + vbt.x;
    o.y = (va.y - mean) * r * vg.y + vbt.y;
    o.z = (va.z - mean) * r * vg.z + vbt.z;
    o.w = (va.w - mean) * r * vg.w + vbt.w;
    if (out_f32) *(float4*)(out_f32 + (size_t)row * D_ + c4) = o;
    if (out_bf16) {
        unsigned p0 = ((unsigned)(unsigned short)f2bf(o.x)) | (((unsigned)(unsigned short)f2bf(o.y)) << 16);
        unsigned p1 = ((unsigned)(unsigned short)f2bf(o.z)) | (((unsigned)(unsigned short)f2bf(o.w)) << 16);
        int2 pk = make_int2((int)p0, (int)p1);
        *(int2*)((short*)out_bf16 + (size_t)row * D_ + c4) = pk;
    }
}

// ---------------- unified GEMM: 256x128 tile, 8 waves 4Mx2N, 3-deep bufs, counted vmcnt ----------------
// The gemm2_k structure (verified r5-r9), templated on epilogue.
// EPI 0: relu -> bf16 out;  EPI 2: fp32 out + bf16 residual RES.
// K-tile t in buf t%3, stage t+2 into buf (t+2)%3; vmcnt(6) at top (tile t+1's 6 issues
// stay in flight); ONE barrier per K-tile. T2 swizzle both-sides, T1 XCD swizzle.
template <int EPI>
__global__ __launch_bounds__(512, 1) void gemmk(const bf16* __restrict__ A,
                                                const bf16* __restrict__ Bw,
                                                const float* __restrict__ bias,
                                                const bf16* __restrict__ RES,
                                                void* __restrict__ Cout,
                                                int M, int N, int K) {
    __shared__ short As[3][256 * 64];
    __shared__ short Bs[3][128 * 64];

    const int tid = threadIdx.x;
    const int wid = tid >> 6, lane = tid & 63;
    const int wr = wid >> 1, wc = wid & 1;       // 4M x 2N waves, 64x64 out each
    const int lrow = lane & 15, quad = lane >> 4;

    // T1 bijective XCD swizzle (grid % 8 == 0: 1024 / 256 wg)
    const int nbx = gridDim.x;
    const int id = blockIdx.y * nbx + blockIdx.x;
    const int chunk = (nbx * gridDim.y) >> 3;
    const int swz = (id & 7) * chunk + (id >> 3);
    const int bn = swz % nbx, bm = swz / nbx;

    const int srow = wid * 8 + (lane >> 3);
    const int scol = ((lane & 7) ^ ((lane >> 3) & 7)) * 8;   // pre-permuted source (T2, rule 21)
    const short* Ag = (const short*)A + (size_t)(bm * 256 + srow) * K + scol;
    const short* Bg = (const short*)Bw + (size_t)(bn * 128 + srow) * K + scol;

    f32x4 acc[4][4];
#pragma unroll
    for (int i = 0; i < 4; i++)
#pragma unroll
        for (int j = 0; j < 4; j++) acc[i][j] = (f32x4){0.f, 0.f, 0.f, 0.f};

#define STAGE2_A(dst, k0)                                                            \
    do {                                                                             \
        _Pragma("unroll") for (int s = 0; s < 4; s++)                                \
            gl_lds16(Ag + (size_t)s * 64 * K + (k0), (dst) + (s * 64 + wid * 8) * 64); \
    } while (0)
#define STAGE2_B(dst, k0)                                                            \
    do {                                                                             \
        _Pragma("unroll") for (int s = 0; s < 2; s++)                                \
            gl_lds16(Bg + (size_t)s * 64 * K + (k0), (dst) + (s * 64 + wid * 8) * 64); \
    } while (0)
#define RD2(base, R, q) (*(const short8*)&(base)[(R) * 64 + (((q) ^ ((R) & 7)) * 8)])
#define LGKM0()                                            \
    do {                                                   \
        asm volatile("s_waitcnt lgkmcnt(0)" ::: "memory"); \
        __builtin_amdgcn_sched_barrier(0);                 \
    } while (0)

    short* a0 = &As[0][0];
    short* a1 = &As[1][0];
    short* a2 = &As[2][0];
    short* b0 = &Bs[0][0];
    short* b1 = &Bs[1][0];
    short* b2 = &Bs[2][0];

    STAGE2_A(a0, 0);
    STAGE2_B(b0, 0);
    STAGE2_A(a1, 64);
    STAGE2_B(b1, 64);

    const int NT = K / 64;
    for (int t = 0; t < NT; t++) {
        if (t < NT - 1)
            asm volatile("s_waitcnt vmcnt(6)" ::: "memory");
        else
            asm volatile("s_waitcnt vmcnt(0)" ::: "memory");
        __builtin_amdgcn_s_barrier();
        __builtin_amdgcn_sched_barrier(0);
        const bool more = t + 2 < NT;
        const int kn = (t + 2) * 64;

        short8 afr[4][2], bfr[4][2];
#pragma unroll
        for (int i = 0; i < 4; i++)
#pragma unroll
            for (int kq = 0; kq < 2; kq++)
                afr[i][kq] = RD2(a0, wr * 64 + i * 16 + lrow, kq * 4 + quad);
#pragma unroll
        for (int j = 0; j < 2; j++)
#pragma unroll
            for (int kq = 0; kq < 2; kq++)
                bfr[j][kq] = RD2(b0, wc * 64 + j * 16 + lrow, kq * 4 + quad);
        if (more) STAGE2_A(a2, kn);
        LGKM0();
        __builtin_amdgcn_s_setprio(1);
#pragma unroll
        for (int i = 0; i < 4; i++)
#pragma unroll
            for (int j = 0; j < 2; j++)
#pragma unroll
                for (int kq = 0; kq < 2; kq++)
                    acc[i][j] = __builtin_amdgcn_mfma_f32_16x16x32_bf16(
                        afr[i][kq], bfr[j][kq], acc[i][j], 0, 0, 0);
        __builtin_amdgcn_s_setprio(0);

#pragma unroll
        for (int j = 2; j < 4; j++)
#pragma unroll
            for (int kq = 0; kq < 2; kq++)
                bfr[j][kq] = RD2(b0, wc * 64 + j * 16 + lrow, kq * 4 + quad);
        if (more) STAGE2_B(b2, kn);
        LGKM0();
        __builtin_amdgcn_s_setprio(1);
#pragma unroll
        for (int i = 0; i < 4; i++)
#pragma unroll
            for (int j = 2; j < 4; j++)
#pragma unroll
                for (int kq = 0; kq < 2; kq++)
                    acc[i][j] = __builtin_amdgcn_mfma_f32_16x16x32_bf16(
                        afr[i][kq], bfr[j][kq], acc[i][j], 0, 0, 0);
        __builtin_amdgcn_s_setprio(0);

        short* ta = a0; a0 = a1; a1 = a2; a2 = ta;
        short* tb = b0; b0 = b1; b1 = b2; b2 = tb;
    }
#undef STAGE2_A
#undef STAGE2_B
#undef RD2
#undef LGKM0

#pragma unroll
    for (int i = 0; i < 4; i++)
#pragma unroll
        for (int j = 0; j < 4; j++) {
            int col = bn * 128 + wc * 64 + j * 16 + lrow;
            float bv = bias[col];
#pragma unroll
            for (int r = 0; r < 4; r++) {
                int row = bm * 256 + wr * 64 + i * 16 + quad * 4 + r;
                float v = acc[i][j][r] + bv;
                if (EPI == 0) {
                    v = fmaxf(v, 0.f);
                    ((bf16*)Cout)[(size_t)row * N + col] = __float2bfloat16(v);
                } else {
                    v += __bfloat162float(RES[(size_t)row * N + col]);
                    ((float*)Cout)[(size_t)row * N + col] = v;
                }
            }
        }
}

// ---------------- launch ----------------
extern "C" void kernel_launch(void* const* d_in, const int* in_sizes, int n_in,
                              void* d_out, int out_size, void* d_ws, size_t ws_size,
                              hipStream_t stream) {
    const float* x = (const float*)d_in[0];
    const float* w1 = (const float*)d_in[1];
    const float* b1 = (const float*)d_in[2];
    const float* w2 = (const float*)d_in[3];
    const float* b2 = (const float*)d_in[4];
    const float* g1 = (const float*)d_in[5];
    const float* be1 = (const float*)d_in[6];
    const float* g2 = (const float*)d_in[7];
    const float* be2 = (const float*)d_in[8];
    float* out = (float*)d_out;

    char* ws = (char*)d_ws;
    const size_t MB = 1024 * 1024;
    float* attn_out = (float*)(ws);            // 32 MiB
    bf16* x1b = (bf16*)(ws + 64 * MB);         // 16 MiB (LN1 out, bf16: gemm1 A + gemm2 RES)
    bf16* w1b = (bf16*)(ws + 80 * MB);         // 8 MiB
    bf16* w2b = (bf16*)(ws + 88 * MB);         // 8 MiB
    bf16* hb = (bf16*)(ws + 96 * MB);          // 64 MiB (GEMM phase)
    // attention-phase buffers alias hb's region (dead once gemm1 runs):
    short* xb = (short*)(ws + 96 * MB);        // 16 MiB bf16 x
    short* vt = (short*)(ws + 112 * MB);       // 16 MiB bf16 x^T per (b,h)
    float* y2 = attn_out;                      // reuse

    convert_bf16_kernel<<<4096, 256, 0, stream>>>(w1, w1b, F_ * D_);
    convert_bf16_kernel<<<4096, 256, 0, stream>>>(w2, w2b, D_ * F_);
    transpose_vt_kernel<<<dim3(B_ * H_, L_ / 64), 256, 0, stream>>>(x, vt, xb);

    flash_attn_kernel<<<B_ * H_ * (L_ / 128), 256, 0, stream>>>(x, xb, vt, attn_out);

    // LN1: bf16 out only (residual for gemm2 is read back as bf16)
    ln_kernel<<<B_ * L_, 256, 0, stream>>>(x, attn_out, g1, be1, nullptr, x1b);

    // gemm1: M=8192, N=4096, K=1024 -> grid 32 x 32 = 1024 wg (gemm2_k structure)
    gemmk<0><<<dim3(F_ / 128, (B_ * L_) / 256), 512, 0, stream>>>(
        x1b, w1b, b1, nullptr, (void*)hb, B_ * L_, F_, D_);
    // gemm2: M=8192, N=1024, K=4096 -> grid 8 x 32 = 256 wg
    gemmk<2><<<dim3(D_ / 128, (B_ * L_) / 256), 512, 0, stream>>>(
        hb, w2b, b2, x1b, (void*)y2, B_ * L_, D_, F_);

    ln_kernel<<<B_ * L_, 256, 0, stream>>>(y2, nullptr, g2, be2, out, nullptr);
}

// Round 11
// 254.978 us; speedup vs baseline: 1.0426x; 1.0354x over previous
//
#include <hip/hip_runtime.h>
#include <hip/hip_bf16.h>

#define B_ 4
#define L_ 2048
#define D_ 1024
#define F_ 4096
#define H_ 16
#define E_ 64

typedef __hip_bfloat16 bf16;
typedef __attribute__((ext_vector_type(8))) short short8;
typedef __attribute__((ext_vector_type(4))) float f32x4;
typedef __attribute__((ext_vector_type(16))) float f32x16;

__device__ __forceinline__ short f2bf(float f) {
    union { float f; unsigned u; } v;
    v.f = f;
    unsigned r = (v.u + 0x7fff + ((v.u >> 16) & 1)) >> 16;
    return (short)r;
}

// async global->LDS, 16B per lane, lands at ldsbase + lane*16
__device__ __forceinline__ void gl_lds16(const short* g, short* l) {
    __builtin_amdgcn_global_load_lds((const __attribute__((address_space(1))) void*)g,
                                     (__attribute__((address_space(3))) void*)l, 16, 0, 0);
}

// ---------------- fp32 -> bf16 convert ----------------
__global__ __launch_bounds__(256) void convert_bf16_kernel(const float* __restrict__ src,
                                                           bf16* __restrict__ dst, int n) {
    int i = (blockIdx.x * 256 + threadIdx.x) * 4;
    if (i + 3 < n) {
        float4 v = *(const float4*)(src + i);
        dst[i + 0] = __float2bfloat16(v.x);
        dst[i + 1] = __float2bfloat16(v.y);
        dst[i + 2] = __float2bfloat16(v.z);
        dst[i + 3] = __float2bfloat16(v.w);
    }
}

// ---------------- V^T pre-pass + bf16 x copy ----------------
__global__ __launch_bounds__(256) void transpose_vt_kernel(const float* __restrict__ x,
                                                           short* __restrict__ vt,
                                                           short* __restrict__ xb) {
    __shared__ float tile[64][65];
    const int bh = blockIdx.x, lt = blockIdx.y;
    const int b = bh >> 4, h = bh & 15;
    const int l0 = lt * 64;
    for (int idx = threadIdx.x; idx < 4096; idx += 256) {
        int r = idx >> 6, c = idx & 63;
        float v = x[((size_t)b * L_ + l0 + r) * D_ + h * E_ + c];
        tile[r][c] = v;
        xb[((size_t)b * L_ + l0 + r) * D_ + h * E_ + c] = f2bf(v);
    }
    __syncthreads();
    for (int idx = threadIdx.x; idx < 4096; idx += 256) {
        int e = idx >> 6, l = idx & 63;
        vt[((size_t)bh * E_ + e) * L_ + l0 + l] = f2bf(tile[l][e]);
    }
}

// ---------------- flash attention, swapped-operand 32x32 MFMA, in-register P ----------------
// grid 1024; XCD-grouping swizzle (id&7 owns 8 heads = 4MB K/V = its L2).
// K/V via global_load_lds into unpadded KV[2][2][64][64], row-half-invariant XOR swizzle
// (phys chunk = logical ^ (r&7), both-sides). l-sum = per-lane VALU accumulation
// (r7-measured config: ones-MFMA l-sum was 2us SLOWER - MFMA pipe is the tighter one).
__global__ __launch_bounds__(256, 4) void flash_attn_kernel(const float* __restrict__ x,
                                                            const short* __restrict__ xb,
                                                            const short* __restrict__ vt,
                                                            float* __restrict__ attn_out) {
    __shared__ short KV[2][2][64][64];   // [buf][K=0/V=1][row][chunk*8]

    const int tid = threadIdx.x;
    const int w = tid >> 6, lane = tid & 63;
    const int l31 = lane & 31;
    const int hi = lane >> 5;
    const int hi8 = hi * 8;

    // XCD-grouping bijection: blocks of one (b,h) stay on one XCD
    const int orig = blockIdx.x;
    const int xcd = orig & 7;
    const int seq = orig >> 3;
    const int qt = seq & 15;
    const int bh = ((seq >> 4) << 3) | xcd;
    const int b = bh >> 4, h = bh & 15;
    const int q0 = qt * 128;

    const short* kbase = xb + (size_t)b * L_ * D_ + h * E_;

    const float QS = 0.125f * 1.44269504f;
    const int qrow = q0 + w * 32 + l31;
    short8 qf[4];
    {
        const float* qp = x + ((size_t)b * L_ + qrow) * D_ + h * E_;
#pragma unroll
        for (int ks = 0; ks < 4; ks++) {
            float4 v0 = *(const float4*)(qp + ks * 16 + hi8);
            float4 v1 = *(const float4*)(qp + ks * 16 + hi8 + 4);
            short8 sc;
            sc[0] = f2bf(v0.x * QS); sc[1] = f2bf(v0.y * QS);
            sc[2] = f2bf(v0.z * QS); sc[3] = f2bf(v0.w * QS);
            sc[4] = f2bf(v1.x * QS); sc[5] = f2bf(v1.y * QS);
            sc[6] = f2bf(v1.z * QS); sc[7] = f2bf(v1.w * QS);
            qf[ks] = sc;
        }
    }

    f32x16 acc_o[2];
    float lsum = 0.f;
#pragma unroll
    for (int r = 0; r < 16; r++) { acc_o[0][r] = 0.f; acc_o[1][r] = 0.f; }

    // staging: wave w covers rows [w*16, w*16+16) of K and of V; 4 issues/wave.
    // source chunk pre-permuted: phys chunk (lane&7) at row r holds logical (lane&7)^(r&7).
    const int srow = lane >> 3;                       // 0..7 within 8-row issue
    const int schunk = ((lane & 7) ^ srow) * 8;       // logical chunk this lane fetches
    const short* ksrc0 = kbase + (size_t)(w * 16 + srow) * D_ + schunk;
    const short* vsrc0 = vt + ((size_t)bh * E_ + w * 16 + srow) * L_ + schunk;

#define STAGEF(bf_, t_)                                                     \
    do {                                                                    \
        const short* ks_ = ksrc0 + (size_t)(t_) * 64 * D_;                  \
        gl_lds16(ks_, &KV[bf_][0][w * 16][0]);                              \
        gl_lds16(ks_ + (size_t)8 * D_, &KV[bf_][0][w * 16 + 8][0]);         \
        const short* vs_ = vsrc0 + (size_t)(t_) * 64;                       \
        gl_lds16(vs_, &KV[bf_][1][w * 16][0]);                              \
        gl_lds16(vs_ + (size_t)8 * L_, &KV[bf_][1][w * 16 + 8][0]);         \
    } while (0)

    // per-lane read base: phys chunk of logical chunk (hi) at row l31; valid for rows
    // l31 and 32+l31 alike since the swizzle term is (r&7).
    const int p0 = l31 * 128 + ((((l31 & 7) ^ hi)) << 4);

    STAGEF(0, 0);   // prefetch tile 0

    const int NT = L_ / 64;
    for (int t = 0; t < NT; t++) {
        const int cur = t & 1;
        __syncthreads();   // drains vmcnt(0): tile t landed; all prior reads done

        if (t + 1 < NT) STAGEF(cur ^ 1, t + 1);   // covered by the compute below

        const char* kvb = (const char*)&KV[cur][0][0][0];

        f32x16 accp0, accp1;
#pragma unroll
        for (int r = 0; r < 16; r++) { accp0[r] = 0.f; accp1[r] = 0.f; }
        __builtin_amdgcn_s_setprio(1);
#pragma unroll
        for (int j = 0; j < 4; j++) {
            short8 kf0 = *(const short8*)(kvb + (p0 ^ (j << 5)));
            short8 kf1 = *(const short8*)(kvb + 4096 + (p0 ^ (j << 5)));
            accp0 = __builtin_amdgcn_mfma_f32_32x32x16_bf16(kf0, qf[j], accp0, 0, 0, 0);
            accp1 = __builtin_amdgcn_mfma_f32_32x32x16_bf16(kf1, qf[j], accp1, 0, 0, 0);
        }
        __builtin_amdgcn_s_setprio(0);

        float pe[2][16];
#pragma unroll
        for (int r = 0; r < 16; r++) {
            pe[0][r] = __builtin_amdgcn_exp2f(accp0[r]);
            pe[1][r] = __builtin_amdgcn_exp2f(accp1[r]);
        }
        // per-lane l partial: lane owns q=l31 column; own 32 of 64 s-rows (partner has rest)
#pragma unroll
        for (int r = 0; r < 16; r++) lsum += pe[0][r] + pe[1][r];

#pragma unroll
        for (int j = 0; j < 4; j++) {
            const int tt = j >> 1, o = (j & 1) * 8;
            unsigned X0, X1, Y0, Y1;
            asm("v_cvt_pk_bf16_f32 %0, %1, %2" : "=v"(X0) : "v"(pe[tt][o + 0]), "v"(pe[tt][o + 1]));
            asm("v_cvt_pk_bf16_f32 %0, %1, %2" : "=v"(X1) : "v"(pe[tt][o + 2]), "v"(pe[tt][o + 3]));
            asm("v_cvt_pk_bf16_f32 %0, %1, %2" : "=v"(Y0) : "v"(pe[tt][o + 4]), "v"(pe[tt][o + 5]));
            asm("v_cvt_pk_bf16_f32 %0, %1, %2" : "=v"(Y1) : "v"(pe[tt][o + 6]), "v"(pe[tt][o + 7]));
            asm("v_permlane32_swap_b32 %0, %1" : "+v"(X0), "+v"(Y0));
            asm("v_permlane32_swap_b32 %0, %1" : "+v"(X1), "+v"(Y1));
            int4 wi = make_int4((int)X0, (int)X1, (int)Y0, (int)Y1);
            short8 pb = *(short8*)&wi;

            __builtin_amdgcn_s_setprio(1);
            short8 vf0 = *(const short8*)(kvb + 8192 + (p0 ^ (j << 5)));
            short8 vf1 = *(const short8*)(kvb + 12288 + (p0 ^ (j << 5)));
            acc_o[0] = __builtin_amdgcn_mfma_f32_32x32x16_bf16(vf0, pb, acc_o[0], 0, 0, 0);
            acc_o[1] = __builtin_amdgcn_mfma_f32_32x32x16_bf16(vf1, pb, acc_o[1], 0, 0, 0);
            __builtin_amdgcn_s_setprio(0);
        }
    }
#undef STAGEF

    // epilogue: O /= l.  l = own partial + hi-partner partial (same q column).
    const float ltot = lsum + __shfl_xor(lsum, 32, 64);
    const float il = 1.0f / ltot;
    float* op = attn_out + ((size_t)b * L_ + qrow) * D_ + h * E_ + hi * 4;
#pragma unroll
    for (int et = 0; et < 2; et++)
#pragma unroll
        for (int rg = 0; rg < 4; rg++) {
            float4 ov;
            ov.x = acc_o[et][rg * 4 + 0] * il;
            ov.y = acc_o[et][rg * 4 + 1] * il;
            ov.z = acc_o[et][rg * 4 + 2] * il;
            ov.w = acc_o[et][rg * 4 + 3] * il;
            *(float4*)(op + et * 32 + rg * 8) = ov;
        }
}

// ---------------- residual + layernorm (vectorized), optional second input ----------------
__global__ __launch_bounds__(256) void ln_kernel(const float* __restrict__ A,
                                                 const float* __restrict__ Bres,
                                                 const float* __restrict__ gamma,
                                                 const float* __restrict__ beta,
                                                 float* __restrict__ out_f32,
                                                 bf16* __restrict__ out_bf16) {
    __shared__ float reds[4], reds2[4];
    const int row = blockIdx.x, tid = threadIdx.x;
    const int c4 = tid * 4;
    float4 va = *(const float4*)(A + (size_t)row * D_ + c4);
    if (Bres) {
        float4 vb = *(const float4*)(Bres + (size_t)row * D_ + c4);
        va.x += vb.x; va.y += vb.y; va.z += vb.z; va.w += vb.w;
    }
    float s = va.x + va.y + va.z + va.w;
    float s2 = va.x * va.x + va.y * va.y + va.z * va.z + va.w * va.w;
#pragma unroll
    for (int o = 32; o > 0; o >>= 1) {
        s += __shfl_down(s, o, 64);
        s2 += __shfl_down(s2, o, 64);
    }
    if ((tid & 63) == 0) { reds[tid >> 6] = s; reds2[tid >> 6] = s2; }
    __syncthreads();
    s = reds[0] + reds[1] + reds[2] + reds[3];
    s2 = reds2[0] + reds2[1] + reds2[2] + reds2[3];
    float mean = s * (1.0f / D_);
    float var = s2 * (1.0f / D_) - mean * mean;
    float r = rsqrtf(var + 1e-5f);
    float4 vg = *(const float4*)(gamma + c4);
    float4 vbt = *(const float4*)(beta + c4);
    float4 o;
    o.x = (va.x - mean) * r * vg.x + vbt.x;
    o.y = (va.y - mean) * r * vg.y + vbt.y;
    o.z = (va.z - mean) * r * vg.z + vbt.z;
    o.w = (va.w - mean) * r * vg.w + vbt.w;
    if (out_f32) *(float4*)(out_f32 + (size_t)row * D_ + c4) = o;
    if (out_bf16) {
        unsigned p0 = ((unsigned)(unsigned short)f2bf(o.x)) | (((unsigned)(unsigned short)f2bf(o.y)) << 16);
        unsigned p1 = ((unsigned)(unsigned short)f2bf(o.z)) | (((unsigned)(unsigned short)f2bf(o.w)) << 16);
        int2 pk = make_int2((int)p0, (int)p1);
        *(int2*)((short*)out_bf16 + (size_t)row * D_ + c4) = pk;
    }
}

// ---------------- gemm1 persistent: 256x128 tiles, block sweeps 4 bn, continuous pipeline ----------------
// Same 3-deep counted-vmcnt discipline as gemmk, but grid = 256 wg (1/CU) and each block
// runs GT = 4*NT continuous K-tiles over 4 consecutive bn panels. At chunk boundaries the
// epilogue stores are issued BEFORE the next chunk's staging, so FIFO order is
// [older loads][stores][new loads] and the top-of-tile vmcnt(6) keeps the new loads in flight.
__global__ __launch_bounds__(512, 1) void gemm1_p(const bf16* __restrict__ A,
                                                  const bf16* __restrict__ Bw,
                                                  const float* __restrict__ bias,
                                                  bf16* __restrict__ Cout,
                                                  int M, int N, int K) {
    __shared__ short As[3][256 * 64];
    __shared__ short Bs[3][128 * 64];

    const int tid = threadIdx.x;
    const int wid = tid >> 6, lane = tid & 63;
    const int wr = wid >> 1, wc = wid & 1;       // 4M x 2N waves, 64x64 out each
    const int lrow = lane & 15, quad = lane >> 4;

    // T1 bijective XCD swizzle on 256 wg (gridDim = 8 x 32)
    const int nbx = gridDim.x;
    const int id = blockIdx.y * nbx + blockIdx.x;
    const int chunk = (nbx * gridDim.y) >> 3;
    const int swz = (id & 7) * chunk + (id >> 3);
    const int bxs = swz % nbx, bm = swz / nbx;
    const int bn_base = bxs * 4;                 // 4 consecutive bn tiles (512 cols)

    const int srow = wid * 8 + (lane >> 3);
    const int scol = ((lane & 7) ^ ((lane >> 3) & 7)) * 8;   // pre-permuted source (T2)
    const short* Ag = (const short*)A + (size_t)(bm * 256 + srow) * K + scol;
    const short* Bg0 = (const short*)Bw + (size_t)(bn_base * 128 + srow) * K + scol;

    f32x4 acc[4][4];
#pragma unroll
    for (int i = 0; i < 4; i++)
#pragma unroll
        for (int j = 0; j < 4; j++) acc[i][j] = (f32x4){0.f, 0.f, 0.f, 0.f};

#define STAGE_A(dst, k0)                                                             \
    do {                                                                             \
        _Pragma("unroll") for (int s = 0; s < 4; s++)                                \
            gl_lds16(Ag + (size_t)s * 64 * K + (k0), (dst) + (s * 64 + wid * 8) * 64); \
    } while (0)
#define STAGE_B(dst, c, k0)                                                          \
    do {                                                                             \
        const short* bgc_ = Bg0 + (size_t)(c) * 128 * K;                             \
        _Pragma("unroll") for (int s = 0; s < 2; s++)                                \
            gl_lds16(bgc_ + (size_t)s * 64 * K + (k0), (dst) + (s * 64 + wid * 8) * 64); \
    } while (0)
#define RD(base, R, q) (*(const short8*)&(base)[(R) * 64 + (((q) ^ ((R) & 7)) * 8)])
#define LGKM0()                                            \
    do {                                                   \
        asm volatile("s_waitcnt lgkmcnt(0)" ::: "memory"); \
        __builtin_amdgcn_sched_barrier(0);                 \
    } while (0)

    short* a0 = &As[0][0];
    short* a1 = &As[1][0];
    short* a2 = &As[2][0];
    short* b0 = &Bs[0][0];
    short* b1 = &Bs[1][0];
    short* b2 = &Bs[2][0];

    const int NT = K / 64;       // 16
    const int GT = 4 * NT;       // 64 continuous K-tiles

    // prologue: global tiles 0 and 1 (both in chunk 0)
    STAGE_A(a0, 0);
    STAGE_B(b0, 0, 0);
    STAGE_A(a1, 64);
    STAGE_B(b1, 0, 64);

    int kks = 128, cs = 0;       // k-offset / chunk of tile g+2
    int kt = 0, c_cur = 0;       // k-index within chunk / current chunk

    for (int g = 0; g < GT; g++) {
        if (g < GT - 1)
            asm volatile("s_waitcnt vmcnt(6)" ::: "memory");
        else
            asm volatile("s_waitcnt vmcnt(0)" ::: "memory");
        __builtin_amdgcn_s_barrier();
        __builtin_amdgcn_sched_barrier(0);
        const bool more = g + 2 < GT;
        const bool bd = (kt == NT - 1);          // last K-tile of this chunk

        short8 afr[4][2], bfr[4][2];
#pragma unroll
        for (int i = 0; i < 4; i++)
#pragma unroll
            for (int kq = 0; kq < 2; kq++)
                afr[i][kq] = RD(a0, wr * 64 + i * 16 + lrow, kq * 4 + quad);
#pragma unroll
        for (int j = 0; j < 2; j++)
#pragma unroll
            for (int kq = 0; kq < 2; kq++)
                bfr[j][kq] = RD(b0, wc * 64 + j * 16 + lrow, kq * 4 + quad);
        if (more && !bd) STAGE_A(a2, kks);
        LGKM0();
        __builtin_amdgcn_s_setprio(1);
#pragma unroll
        for (int i = 0; i < 4; i++)
#pragma unroll
            for (int j = 0; j < 2; j++)
#pragma unroll
                for (int kq = 0; kq < 2; kq++)
                    acc[i][j] = __builtin_amdgcn_mfma_f32_16x16x32_bf16(
                        afr[i][kq], bfr[j][kq], acc[i][j], 0, 0, 0);
        __builtin_amdgcn_s_setprio(0);

#pragma unroll
        for (int j = 2; j < 4; j++)
#pragma unroll
            for (int kq = 0; kq < 2; kq++)
                bfr[j][kq] = RD(b0, wc * 64 + j * 16 + lrow, kq * 4 + quad);
        if (more && !bd) STAGE_B(b2, cs, kks);
        LGKM0();
        __builtin_amdgcn_s_setprio(1);
#pragma unroll
        for (int i = 0; i < 4; i++)
#pragma unroll
            for (int j = 2; j < 4; j++)
#pragma unroll
                for (int kq = 0; kq < 2; kq++)
                    acc[i][j] = __builtin_amdgcn_mfma_f32_16x16x32_bf16(
                        afr[i][kq], bfr[j][kq], acc[i][j], 0, 0, 0);
        __builtin_amdgcn_s_setprio(0);

        if (bd) {
            // epilogue for chunk c_cur (stores issued BEFORE next chunk's staging)
            const int colb = (bn_base + c_cur) * 128 + wc * 64;
#pragma unroll
            for (int i = 0; i < 4; i++)
#pragma unroll
                for (int j = 0; j < 4; j++) {
                    int col = colb + j * 16 + lrow;
                    float bv = bias[col];
#pragma unroll
                    for (int r = 0; r < 4; r++) {
                        int row = bm * 256 + wr * 64 + i * 16 + quad * 4 + r;
                        float v = fmaxf(acc[i][j][r] + bv, 0.f);
                        Cout[(size_t)row * N + col] = __float2bfloat16(v);
                    }
                    acc[i][j] = (f32x4){0.f, 0.f, 0.f, 0.f};
                }
            if (more) {
                STAGE_A(a2, kks);
                STAGE_B(b2, cs, kks);
            }
            c_cur++;
            kt = 0;
        } else {
            kt++;
        }

        kks += 64;
        if (kks == K) { kks = 0; cs++; }

        short* ta = a0; a0 = a1; a1 = a2; a2 = ta;
        short* tb = b0; b0 = b1; b1 = b2; b2 = tb;
    }
#undef STAGE_A
#undef STAGE_B
#undef RD
#undef LGKM0
}

// ---------------- gemm2: 256x128 tile, 8 waves 4Mx2N, 3-deep buffers, counted vmcnt ----------------
// fp32 out + bf16 residual RES.
__global__ __launch_bounds__(512, 1) void gemm2_k(const bf16* __restrict__ A,
                                                  const bf16* __restrict__ Bw,
                                                  const float* __restrict__ bias,
                                                  const bf16* __restrict__ RES,
                                                  float* __restrict__ Cout,
                                                  int M, int N, int K) {
    __shared__ short As[3][256 * 64];
    __shared__ short Bs[3][128 * 64];

    const int tid = threadIdx.x;
    const int wid = tid >> 6, lane = tid & 63;
    const int wr = wid >> 1, wc = wid & 1;       // 4M x 2N waves, 64x64 out each
    const int lrow = lane & 15, quad = lane >> 4;

    const int nbx = gridDim.x;
    const int id = blockIdx.y * nbx + blockIdx.x;
    const int chunk = (nbx * gridDim.y) >> 3;
    const int swz = (id & 7) * chunk + (id >> 3);
    const int bn = swz % nbx, bm = swz / nbx;

    const int srow = wid * 8 + (lane >> 3);
    const int scol = ((lane & 7) ^ ((lane >> 3) & 7)) * 8;   // pre-permuted source (T2)
    const short* Ag = (const short*)A + (size_t)(bm * 256 + srow) * K + scol;
    const short* Bg = (const short*)Bw + (size_t)(bn * 128 + srow) * K + scol;

    f32x4 acc[4][4];
#pragma unroll
    for (int i = 0; i < 4; i++)
#pragma unroll
        for (int j = 0; j < 4; j++) acc[i][j] = (f32x4){0.f, 0.f, 0.f, 0.f};

#define STAGE2_A(dst, k0)                                                            \
    do {                                                                             \
        _Pragma("unroll") for (int s = 0; s < 4; s++)                                \
            gl_lds16(Ag + (size_t)s * 64 * K + (k0), (dst) + (s * 64 + wid * 8) * 64); \
    } while (0)
#define STAGE2_B(dst, k0)                                                            \
    do {                                                                             \
        _Pragma("unroll") for (int s = 0; s < 2; s++)                                \
            gl_lds16(Bg + (size_t)s * 64 * K + (k0), (dst) + (s * 64 + wid * 8) * 64); \
    } while (0)
#define RD2(base, R, q) (*(const short8*)&(base)[(R) * 64 + (((q) ^ ((R) & 7)) * 8)])
#define LGKM0()                                            \
    do {                                                   \
        asm volatile("s_waitcnt lgkmcnt(0)" ::: "memory"); \
        __builtin_amdgcn_sched_barrier(0);                 \
    } while (0)

    short* a0 = &As[0][0];
    short* a1 = &As[1][0];
    short* a2 = &As[2][0];
    short* b0 = &Bs[0][0];
    short* b1 = &Bs[1][0];
    short* b2 = &Bs[2][0];

    STAGE2_A(a0, 0);
    STAGE2_B(b0, 0);
    STAGE2_A(a1, 64);
    STAGE2_B(b1, 64);

    const int NT = K / 64;
    for (int t = 0; t < NT; t++) {
        if (t < NT - 1)
            asm volatile("s_waitcnt vmcnt(6)" ::: "memory");
        else
            asm volatile("s_waitcnt vmcnt(0)" ::: "memory");
        __builtin_amdgcn_s_barrier();
        __builtin_amdgcn_sched_barrier(0);
        const bool more = t + 2 < NT;
        const int kn = (t + 2) * 64;

        short8 afr[4][2], bfr[4][2];
#pragma unroll
        for (int i = 0; i < 4; i++)
#pragma unroll
            for (int kq = 0; kq < 2; kq++)
                afr[i][kq] = RD2(a0, wr * 64 + i * 16 + lrow, kq * 4 + quad);
#pragma unroll
        for (int j = 0; j < 2; j++)
#pragma unroll
            for (int kq = 0; kq < 2; kq++)
                bfr[j][kq] = RD2(b0, wc * 64 + j * 16 + lrow, kq * 4 + quad);
        if (more) STAGE2_A(a2, kn);
        LGKM0();
        __builtin_amdgcn_s_setprio(1);
#pragma unroll
        for (int i = 0; i < 4; i++)
#pragma unroll
            for (int j = 0; j < 2; j++)
#pragma unroll
                for (int kq = 0; kq < 2; kq++)
                    acc[i][j] = __builtin_amdgcn_mfma_f32_16x16x32_bf16(
                        afr[i][kq], bfr[j][kq], acc[i][j], 0, 0, 0);
        __builtin_amdgcn_s_setprio(0);

#pragma unroll
        for (int j = 2; j < 4; j++)
#pragma unroll
            for (int kq = 0; kq < 2; kq++)
                bfr[j][kq] = RD2(b0, wc * 64 + j * 16 + lrow, kq * 4 + quad);
        if (more) STAGE2_B(b2, kn);
        LGKM0();
        __builtin_amdgcn_s_setprio(1);
#pragma unroll
        for (int i = 0; i < 4; i++)
#pragma unroll
            for (int j = 2; j < 4; j++)
#pragma unroll
                for (int kq = 0; kq < 2; kq++)
                    acc[i][j] = __builtin_amdgcn_mfma_f32_16x16x32_bf16(
                        afr[i][kq], bfr[j][kq], acc[i][j], 0, 0, 0);
        __builtin_amdgcn_s_setprio(0);

        short* ta = a0; a0 = a1; a1 = a2; a2 = ta;
        short* tb = b0; b0 = b1; b1 = b2; b2 = tb;
    }
#undef STAGE2_A
#undef STAGE2_B
#undef RD2
#undef LGKM0

#pragma unroll
    for (int i = 0; i < 4; i++)
#pragma unroll
        for (int j = 0; j < 4; j++) {
            int col = bn * 128 + wc * 64 + j * 16 + lrow;
            float bv = bias[col];
#pragma unroll
            for (int r = 0; r < 4; r++) {
                int row = bm * 256 + wr * 64 + i * 16 + quad * 4 + r;
                float v = acc[i][j][r] + bv + __bfloat162float(RES[(size_t)row * N + col]);
                Cout[(size_t)row * N + col] = v;
            }
        }
}

// ---------------- launch ----------------
extern "C" void kernel_launch(void* const* d_in, const int* in_sizes, int n_in,
                              void* d_out, int out_size, void* d_ws, size_t ws_size,
                              hipStream_t stream) {
    const float* x = (const float*)d_in[0];
    const float* w1 = (const float*)d_in[1];
    const float* b1 = (const float*)d_in[2];
    const float* w2 = (const float*)d_in[3];
    const float* b2 = (const float*)d_in[4];
    const float* g1 = (const float*)d_in[5];
    const float* be1 = (const float*)d_in[6];
    const float* g2 = (const float*)d_in[7];
    const float* be2 = (const float*)d_in[8];
    float* out = (float*)d_out;

    char* ws = (char*)d_ws;
    const size_t MB = 1024 * 1024;
    float* attn_out = (float*)(ws);            // 32 MiB
    bf16* x1b = (bf16*)(ws + 64 * MB);         // 16 MiB (LN1 out, bf16: gemm1 A + gemm2 RES)
    bf16* w1b = (bf16*)(ws + 80 * MB);         // 8 MiB
    bf16* w2b = (bf16*)(ws + 88 * MB);         // 8 MiB
    bf16* hb = (bf16*)(ws + 96 * MB);          // 64 MiB (GEMM phase)
    // attention-phase buffers alias hb's region (dead once gemm1 runs):
    short* xb = (short*)(ws + 96 * MB);        // 16 MiB bf16 x
    short* vt = (short*)(ws + 112 * MB);       // 16 MiB bf16 x^T per (b,h)
    float* y2 = attn_out;                      // reuse

    convert_bf16_kernel<<<4096, 256, 0, stream>>>(w1, w1b, F_ * D_);
    convert_bf16_kernel<<<4096, 256, 0, stream>>>(w2, w2b, D_ * F_);
    transpose_vt_kernel<<<dim3(B_ * H_, L_ / 64), 256, 0, stream>>>(x, vt, xb);

    flash_attn_kernel<<<B_ * H_ * (L_ / 128), 256, 0, stream>>>(x, xb, vt, attn_out);

    // LN1: bf16 out only (residual for gemm2 is read back as bf16)
    ln_kernel<<<B_ * L_, 256, 0, stream>>>(x, attn_out, g1, be1, nullptr, x1b);

    // gemm1: M=8192, N=4096, K=1024 -> grid 8 x 32 = 256 wg, persistent over 4 bn each
    gemm1_p<<<dim3(F_ / 512, (B_ * L_) / 256), 512, 0, stream>>>(
        x1b, w1b, b1, hb, B_ * L_, F_, D_);
    // gemm2: M=8192, N=1024, K=4096 -> grid 8 x 32 = 256 wg
    gemm2_k<<<dim3(D_ / 128, (B_ * L_) / 256), 512, 0, stream>>>(
        hb, w2b, b2, x1b, y2, B_ * L_, D_, F_);

    ln_kernel<<<B_ * L_, 256, 0, stream>>>(y2, nullptr, g2, be2, out, nullptr);
}

// Round 12
// 250.095 us; speedup vs baseline: 1.0630x; 1.0195x over previous
//
#include <hip/hip_runtime.h>
#include <hip/hip_bf16.h>

#define B_ 4
#define L_ 2048
#define D_ 1024
#define F_ 4096
#define H_ 16
#define E_ 64

typedef __hip_bfloat16 bf16;
typedef __attribute__((ext_vector_type(8))) short short8;
typedef __attribute__((ext_vector_type(4))) float f32x4;
typedef __attribute__((ext_vector_type(16))) float f32x16;

__device__ __forceinline__ short f2bf(float f) {
    union { float f; unsigned u; } v;
    v.f = f;
    unsigned r = (v.u + 0x7fff + ((v.u >> 16) & 1)) >> 16;
    return (short)r;
}

// async global->LDS, 16B per lane, lands at ldsbase + lane*16
__device__ __forceinline__ void gl_lds16(const short* g, short* l) {
    __builtin_amdgcn_global_load_lds((const __attribute__((address_space(1))) void*)g,
                                     (__attribute__((address_space(3))) void*)l, 16, 0, 0);
}

// ---------------- fp32 -> bf16 convert ----------------
__global__ __launch_bounds__(256) void convert_bf16_kernel(const float* __restrict__ src,
                                                           bf16* __restrict__ dst, int n) {
    int i = (blockIdx.x * 256 + threadIdx.x) * 4;
    if (i + 3 < n) {
        float4 v = *(const float4*)(src + i);
        dst[i + 0] = __float2bfloat16(v.x);
        dst[i + 1] = __float2bfloat16(v.y);
        dst[i + 2] = __float2bfloat16(v.z);
        dst[i + 3] = __float2bfloat16(v.w);
    }
}

// ---------------- V^T pre-pass + bf16 x copy ----------------
__global__ __launch_bounds__(256) void transpose_vt_kernel(const float* __restrict__ x,
                                                           short* __restrict__ vt,
                                                           short* __restrict__ xb) {
    __shared__ float tile[64][65];
    const int bh = blockIdx.x, lt = blockIdx.y;
    const int b = bh >> 4, h = bh & 15;
    const int l0 = lt * 64;
    for (int idx = threadIdx.x; idx < 4096; idx += 256) {
        int r = idx >> 6, c = idx & 63;
        float v = x[((size_t)b * L_ + l0 + r) * D_ + h * E_ + c];
        tile[r][c] = v;
        xb[((size_t)b * L_ + l0 + r) * D_ + h * E_ + c] = f2bf(v);
    }
    __syncthreads();
    for (int idx = threadIdx.x; idx < 4096; idx += 256) {
        int e = idx >> 6, l = idx & 63;
        vt[((size_t)bh * E_ + e) * L_ + l0 + l] = f2bf(tile[l][e]);
    }
}

// ---------------- flash attention, swapped-operand 32x32 MFMA, in-register P ----------------
// grid 1024; XCD-grouping swizzle (id&7 owns 8 heads = 4MB K/V = its L2).
// K/V via global_load_lds into unpadded KV[2][2][64][64], row-half-invariant XOR swizzle.
// l-sum = per-lane VALU accumulation, split into 2 chains (dep-chain relief).
__global__ __launch_bounds__(256, 4) void flash_attn_kernel(const float* __restrict__ x,
                                                            const short* __restrict__ xb,
                                                            const short* __restrict__ vt,
                                                            float* __restrict__ attn_out) {
    __shared__ short KV[2][2][64][64];   // [buf][K=0/V=1][row][chunk*8]

    const int tid = threadIdx.x;
    const int w = tid >> 6, lane = tid & 63;
    const int l31 = lane & 31;
    const int hi = lane >> 5;
    const int hi8 = hi * 8;

    // XCD-grouping bijection: blocks of one (b,h) stay on one XCD
    const int orig = blockIdx.x;
    const int xcd = orig & 7;
    const int seq = orig >> 3;
    const int qt = seq & 15;
    const int bh = ((seq >> 4) << 3) | xcd;
    const int b = bh >> 4, h = bh & 15;
    const int q0 = qt * 128;

    const short* kbase = xb + (size_t)b * L_ * D_ + h * E_;

    const float QS = 0.125f * 1.44269504f;
    const int qrow = q0 + w * 32 + l31;
    short8 qf[4];
    {
        const float* qp = x + ((size_t)b * L_ + qrow) * D_ + h * E_;
#pragma unroll
        for (int ks = 0; ks < 4; ks++) {
            float4 v0 = *(const float4*)(qp + ks * 16 + hi8);
            float4 v1 = *(const float4*)(qp + ks * 16 + hi8 + 4);
            short8 sc;
            sc[0] = f2bf(v0.x * QS); sc[1] = f2bf(v0.y * QS);
            sc[2] = f2bf(v0.z * QS); sc[3] = f2bf(v0.w * QS);
            sc[4] = f2bf(v1.x * QS); sc[5] = f2bf(v1.y * QS);
            sc[6] = f2bf(v1.z * QS); sc[7] = f2bf(v1.w * QS);
            qf[ks] = sc;
        }
    }

    f32x16 acc_o[2];
    float lsum0 = 0.f, lsum1 = 0.f;
#pragma unroll
    for (int r = 0; r < 16; r++) { acc_o[0][r] = 0.f; acc_o[1][r] = 0.f; }

    // staging: wave w covers rows [w*16, w*16+16) of K and of V; 4 issues/wave.
    // source chunk pre-permuted: phys chunk (lane&7) at row r holds logical (lane&7)^(r&7).
    const int srow = lane >> 3;                       // 0..7 within 8-row issue
    const int schunk = ((lane & 7) ^ srow) * 8;       // logical chunk this lane fetches
    const short* ksrc0 = kbase + (size_t)(w * 16 + srow) * D_ + schunk;
    const short* vsrc0 = vt + ((size_t)bh * E_ + w * 16 + srow) * L_ + schunk;

#define STAGEF(bf_, t_)                                                     \
    do {                                                                    \
        const short* ks_ = ksrc0 + (size_t)(t_) * 64 * D_;                  \
        gl_lds16(ks_, &KV[bf_][0][w * 16][0]);                              \
        gl_lds16(ks_ + (size_t)8 * D_, &KV[bf_][0][w * 16 + 8][0]);         \
        const short* vs_ = vsrc0 + (size_t)(t_) * 64;                       \
        gl_lds16(vs_, &KV[bf_][1][w * 16][0]);                              \
        gl_lds16(vs_ + (size_t)8 * L_, &KV[bf_][1][w * 16 + 8][0]);         \
    } while (0)

    // per-lane read base: phys chunk of logical chunk (hi) at row l31; valid for rows
    // l31 and 32+l31 alike since the swizzle term is (r&7).
    const int p0 = l31 * 128 + ((((l31 & 7) ^ hi)) << 4);

    STAGEF(0, 0);   // prefetch tile 0

    const int NT = L_ / 64;
    for (int t = 0; t < NT; t++) {
        const int cur = t & 1;
        __syncthreads();   // drains vmcnt(0): tile t landed; all prior reads done

        if (t + 1 < NT) STAGEF(cur ^ 1, t + 1);   // covered by the compute below

        const char* kvb = (const char*)&KV[cur][0][0][0];

        f32x16 accp0, accp1;
#pragma unroll
        for (int r = 0; r < 16; r++) { accp0[r] = 0.f; accp1[r] = 0.f; }
        __builtin_amdgcn_s_setprio(1);
#pragma unroll
        for (int j = 0; j < 4; j++) {
            short8 kf0 = *(const short8*)(kvb + (p0 ^ (j << 5)));
            short8 kf1 = *(const short8*)(kvb + 4096 + (p0 ^ (j << 5)));
            accp0 = __builtin_amdgcn_mfma_f32_32x32x16_bf16(kf0, qf[j], accp0, 0, 0, 0);
            accp1 = __builtin_amdgcn_mfma_f32_32x32x16_bf16(kf1, qf[j], accp1, 0, 0, 0);
        }
        __builtin_amdgcn_s_setprio(0);

        float pe[2][16];
#pragma unroll
        for (int r = 0; r < 16; r++) {
            pe[0][r] = __builtin_amdgcn_exp2f(accp0[r]);
            pe[1][r] = __builtin_amdgcn_exp2f(accp1[r]);
        }
        // per-lane l partials (two independent chains)
#pragma unroll
        for (int r = 0; r < 16; r++) { lsum0 += pe[0][r]; lsum1 += pe[1][r]; }

#pragma unroll
        for (int j = 0; j < 4; j++) {
            const int tt = j >> 1, o = (j & 1) * 8;
            unsigned X0, X1, Y0, Y1;
            asm("v_cvt_pk_bf16_f32 %0, %1, %2" : "=v"(X0) : "v"(pe[tt][o + 0]), "v"(pe[tt][o + 1]));
            asm("v_cvt_pk_bf16_f32 %0, %1, %2" : "=v"(X1) : "v"(pe[tt][o + 2]), "v"(pe[tt][o + 3]));
            asm("v_cvt_pk_bf16_f32 %0, %1, %2" : "=v"(Y0) : "v"(pe[tt][o + 4]), "v"(pe[tt][o + 5]));
            asm("v_cvt_pk_bf16_f32 %0, %1, %2" : "=v"(Y1) : "v"(pe[tt][o + 6]), "v"(pe[tt][o + 7]));
            asm("v_permlane32_swap_b32 %0, %1" : "+v"(X0), "+v"(Y0));
            asm("v_permlane32_swap_b32 %0, %1" : "+v"(X1), "+v"(Y1));
            int4 wi = make_int4((int)X0, (int)X1, (int)Y0, (int)Y1);
            short8 pb = *(short8*)&wi;

            __builtin_amdgcn_s_setprio(1);
            short8 vf0 = *(const short8*)(kvb + 8192 + (p0 ^ (j << 5)));
            short8 vf1 = *(const short8*)(kvb + 12288 + (p0 ^ (j << 5)));
            acc_o[0] = __builtin_amdgcn_mfma_f32_32x32x16_bf16(vf0, pb, acc_o[0], 0, 0, 0);
            acc_o[1] = __builtin_amdgcn_mfma_f32_32x32x16_bf16(vf1, pb, acc_o[1], 0, 0, 0);
            __builtin_amdgcn_s_setprio(0);
        }
    }
#undef STAGEF

    // epilogue: O /= l.  l = own partial + hi-partner partial (same q column).
    const float lsum = lsum0 + lsum1;
    const float ltot = lsum + __shfl_xor(lsum, 32, 64);
    const float il = 1.0f / ltot;
    float* op = attn_out + ((size_t)b * L_ + qrow) * D_ + h * E_ + hi * 4;
#pragma unroll
    for (int et = 0; et < 2; et++)
#pragma unroll
        for (int rg = 0; rg < 4; rg++) {
            float4 ov;
            ov.x = acc_o[et][rg * 4 + 0] * il;
            ov.y = acc_o[et][rg * 4 + 1] * il;
            ov.z = acc_o[et][rg * 4 + 2] * il;
            ov.w = acc_o[et][rg * 4 + 3] * il;
            *(float4*)(op + et * 32 + rg * 8) = ov;
        }
}

// ---------------- residual + layernorm (vectorized), optional second input ----------------
__global__ __launch_bounds__(256) void ln_kernel(const float* __restrict__ A,
                                                 const float* __restrict__ Bres,
                                                 const float* __restrict__ gamma,
                                                 const float* __restrict__ beta,
                                                 float* __restrict__ out_f32,
                                                 bf16* __restrict__ out_bf16) {
    __shared__ float reds[4], reds2[4];
    const int row = blockIdx.x, tid = threadIdx.x;
    const int c4 = tid * 4;
    float4 va = *(const float4*)(A + (size_t)row * D_ + c4);
    if (Bres) {
        float4 vb = *(const float4*)(Bres + (size_t)row * D_ + c4);
        va.x += vb.x; va.y += vb.y; va.z += vb.z; va.w += vb.w;
    }
    float s = va.x + va.y + va.z + va.w;
    float s2 = va.x * va.x + va.y * va.y + va.z * va.z + va.w * va.w;
#pragma unroll
    for (int o = 32; o > 0; o >>= 1) {
        s += __shfl_down(s, o, 64);
        s2 += __shfl_down(s2, o, 64);
    }
    if ((tid & 63) == 0) { reds[tid >> 6] = s; reds2[tid >> 6] = s2; }
    __syncthreads();
    s = reds[0] + reds[1] + reds[2] + reds[3];
    s2 = reds2[0] + reds2[1] + reds2[2] + reds2[3];
    float mean = s * (1.0f / D_);
    float var = s2 * (1.0f / D_) - mean * mean;
    float r = rsqrtf(var + 1e-5f);
    float4 vg = *(const float4*)(gamma + c4);
    float4 vbt = *(const float4*)(beta + c4);
    float4 o;
    o.x = (va.x - mean) * r * vg.x + vbt.x;
    o.y = (va.y - mean) * r * vg.y + vbt.y;
    o.z = (va.z - mean) * r * vg.z + vbt.z;
    o.w = (va.w - mean) * r * vg.w + vbt.w;
    if (out_f32) *(float4*)(out_f32 + (size_t)row * D_ + c4) = o;
    if (out_bf16) {
        unsigned p0 = ((unsigned)(unsigned short)f2bf(o.x)) | (((unsigned)(unsigned short)f2bf(o.y)) << 16);
        unsigned p1 = ((unsigned)(unsigned short)f2bf(o.z)) | (((unsigned)(unsigned short)f2bf(o.w)) << 16);
        int2 pk = make_int2((int)p0, (int)p1);
        *(int2*)((short*)out_bf16 + (size_t)row * D_ + c4) = pk;
    }
}

// ---------------- gemm1: 256x256 tile, 8 waves 2Mx4N, 2-deep bufs, barrier-drain pipeline ----------------
// Rationale: 256x128 tiles are LDS-port-bound (128 b128 reads/K-tile/CU vs 64-MFMA's 512cy).
// 256x256 cuts LDS reads per FLOP by 25% (wave=128x64: 24 reads / 2x output). Compute per
// K-tile (~1500cy) >> load latency, so the flash-proven 2-deep + __syncthreads-drain skeleton
// suffices (stage t+1 right after barrier; drained by next barrier). LDS 128KB, 1 block/CU.
// T1 XCD swizzle + T2 both-sides XOR swizzle as verified in gemm2_k.
__global__ __launch_bounds__(512, 1) void gemm1_sq(const bf16* __restrict__ A,
                                                   const bf16* __restrict__ Bw,
                                                   const float* __restrict__ bias,
                                                   bf16* __restrict__ Cout,
                                                   int M, int N, int K) {
    __shared__ short As[2][256 * 64];
    __shared__ short Bs[2][256 * 64];

    const int tid = threadIdx.x;
    const int wid = tid >> 6, lane = tid & 63;
    const int wr = wid >> 2, wc = wid & 3;       // 2M x 4N waves, 128x64 out each
    const int lrow = lane & 15, quad = lane >> 4;

    // T1 bijective XCD swizzle (grid = 16 x 32 = 512 wg, %8==0)
    const int nbx = gridDim.x;
    const int id = blockIdx.y * nbx + blockIdx.x;
    const int chunk = (nbx * gridDim.y) >> 3;
    const int swz = (id & 7) * chunk + (id >> 3);
    const int bn = swz % nbx, bm = swz / nbx;

    // staging: wave wid covers rows [wid*32, wid*32+32) of A and of B; 4 issues each.
    // source chunk pre-permuted: phys chunk (lane&7) at row r holds logical (lane&7)^(r&7)
    // (r&7 == lane>>3 for every 8-row issue group).
    const int srow = wid * 32 + (lane >> 3);
    const int scol = ((lane & 7) ^ ((lane >> 3) & 7)) * 8;
    const short* Ag = (const short*)A + (size_t)(bm * 256 + srow) * K + scol;
    const short* Bg = (const short*)Bw + (size_t)(bn * 256 + srow) * K + scol;

    f32x4 acc[8][4];
#pragma unroll
    for (int i = 0; i < 8; i++)
#pragma unroll
        for (int j = 0; j < 4; j++) acc[i][j] = (f32x4){0.f, 0.f, 0.f, 0.f};

#define SQ_STAGE_A(b, k0)                                                              \
    do {                                                                               \
        _Pragma("unroll") for (int s = 0; s < 4; s++)                                  \
            gl_lds16(Ag + (size_t)s * 8 * K + (k0), &As[b][(wid * 32 + s * 8) * 64]);  \
    } while (0)
#define SQ_STAGE_B(b, k0)                                                              \
    do {                                                                               \
        _Pragma("unroll") for (int s = 0; s < 4; s++)                                  \
            gl_lds16(Bg + (size_t)s * 8 * K + (k0), &Bs[b][(wid * 32 + s * 8) * 64]);  \
    } while (0)
#define SQ_RD(base, R, q) (*(const short8*)&(base)[(R) * 64 + (((q) ^ ((R) & 7)) * 8)])
#define LGKM0()                                            \
    do {                                                   \
        asm volatile("s_waitcnt lgkmcnt(0)" ::: "memory"); \
        __builtin_amdgcn_sched_barrier(0);                 \
    } while (0)

    // prologue: stage K-tile 0 into buf 0
    SQ_STAGE_A(0, 0);
    SQ_STAGE_B(0, 0);

    const int NT = K / 64;
    for (int t = 0; t < NT; t++) {
        const int cur = t & 1;
        __syncthreads();   // drains vmcnt(0)+lgkm: tile t landed; all reads of buf cur^1 done
        const bool more = t + 1 < NT;
        const int kn = (t + 1) * 64;

        short8 af[4][2], bfr[4][2];
        // ---- ph0: A rows 0-63 of wave's half + all B; stage A(t+1) ----
#pragma unroll
        for (int i = 0; i < 4; i++)
#pragma unroll
            for (int kq = 0; kq < 2; kq++)
                af[i][kq] = SQ_RD(As[cur], wr * 128 + i * 16 + lrow, kq * 4 + quad);
#pragma unroll
        for (int j = 0; j < 4; j++)
#pragma unroll
            for (int kq = 0; kq < 2; kq++)
                bfr[j][kq] = SQ_RD(Bs[cur], wc * 64 + j * 16 + lrow, kq * 4 + quad);
        if (more) SQ_STAGE_A(cur ^ 1, kn);
        LGKM0();
        __builtin_amdgcn_s_setprio(1);
#pragma unroll
        for (int i = 0; i < 4; i++)
#pragma unroll
            for (int j = 0; j < 4; j++)
#pragma unroll
                for (int kq = 0; kq < 2; kq++)
                    acc[i][j] = __builtin_amdgcn_mfma_f32_16x16x32_bf16(
                        af[i][kq], bfr[j][kq], acc[i][j], 0, 0, 0);
        __builtin_amdgcn_s_setprio(0);

        // ---- ph1: A rows 64-127 (B reused from regs); stage B(t+1) ----
#pragma unroll
        for (int i = 0; i < 4; i++)
#pragma unroll
            for (int kq = 0; kq < 2; kq++)
                af[i][kq] = SQ_RD(As[cur], wr * 128 + 64 + i * 16 + lrow, kq * 4 + quad);
        if (more) SQ_STAGE_B(cur ^ 1, kn);
        LGKM0();
        __builtin_amdgcn_s_setprio(1);
#pragma unroll
        for (int i = 0; i < 4; i++)
#pragma unroll
            for (int j = 0; j < 4; j++)
#pragma unroll
                for (int kq = 0; kq < 2; kq++)
                    acc[4 + i][j] = __builtin_amdgcn_mfma_f32_16x16x32_bf16(
                        af[i][kq], bfr[j][kq], acc[4 + i][j], 0, 0, 0);
        __builtin_amdgcn_s_setprio(0);
    }
#undef SQ_STAGE_A
#undef SQ_STAGE_B
#undef SQ_RD
#undef LGKM0

    // epilogue: relu -> bf16
#pragma unroll
    for (int i = 0; i < 8; i++)
#pragma unroll
        for (int j = 0; j < 4; j++) {
            int col = bn * 256 + wc * 64 + j * 16 + lrow;
            float bv = bias[col];
#pragma unroll
            for (int r = 0; r < 4; r++) {
                int row = bm * 256 + wr * 128 + i * 16 + quad * 4 + r;
                float v = fmaxf(acc[i][j][r] + bv, 0.f);
                Cout[(size_t)row * N + col] = __float2bfloat16(v);
            }
        }
}

// ---------------- gemm2: 256x128 tile, 8 waves 4Mx2N, 3-deep buffers, counted vmcnt ----------------
// fp32 out + bf16 residual RES.
__global__ __launch_bounds__(512, 1) void gemm2_k(const bf16* __restrict__ A,
                                                  const bf16* __restrict__ Bw,
                                                  const float* __restrict__ bias,
                                                  const bf16* __restrict__ RES,
                                                  float* __restrict__ Cout,
                                                  int M, int N, int K) {
    __shared__ short As[3][256 * 64];
    __shared__ short Bs[3][128 * 64];

    const int tid = threadIdx.x;
    const int wid = tid >> 6, lane = tid & 63;
    const int wr = wid >> 1, wc = wid & 1;       // 4M x 2N waves, 64x64 out each
    const int lrow = lane & 15, quad = lane >> 4;

    const int nbx = gridDim.x;
    const int id = blockIdx.y * nbx + blockIdx.x;
    const int chunk = (nbx * gridDim.y) >> 3;
    const int swz = (id & 7) * chunk + (id >> 3);
    const int bn = swz % nbx, bm = swz / nbx;

    const int srow = wid * 8 + (lane >> 3);
    const int scol = ((lane & 7) ^ ((lane >> 3) & 7)) * 8;   // pre-permuted source (T2)
    const short* Ag = (const short*)A + (size_t)(bm * 256 + srow) * K + scol;
    const short* Bg = (const short*)Bw + (size_t)(bn * 128 + srow) * K + scol;

    f32x4 acc[4][4];
#pragma unroll
    for (int i = 0; i < 4; i++)
#pragma unroll
        for (int j = 0; j < 4; j++) acc[i][j] = (f32x4){0.f, 0.f, 0.f, 0.f};

#define STAGE2_A(dst, k0)                                                            \
    do {                                                                             \
        _Pragma("unroll") for (int s = 0; s < 4; s++)                                \
            gl_lds16(Ag + (size_t)s * 64 * K + (k0), (dst) + (s * 64 + wid * 8) * 64); \
    } while (0)
#define STAGE2_B(dst, k0)                                                            \
    do {                                                                             \
        _Pragma("unroll") for (int s = 0; s < 2; s++)                                \
            gl_lds16(Bg + (size_t)s * 64 * K + (k0), (dst) + (s * 64 + wid * 8) * 64); \
    } while (0)
#define RD2(base, R, q) (*(const short8*)&(base)[(R) * 64 + (((q) ^ ((R) & 7)) * 8)])
#define LGKM0()                                            \
    do {                                                   \
        asm volatile("s_waitcnt lgkmcnt(0)" ::: "memory"); \
        __builtin_amdgcn_sched_barrier(0);                 \
    } while (0)

    short* a0 = &As[0][0];
    short* a1 = &As[1][0];
    short* a2 = &As[2][0];
    short* b0 = &Bs[0][0];
    short* b1 = &Bs[1][0];
    short* b2 = &Bs[2][0];

    STAGE2_A(a0, 0);
    STAGE2_B(b0, 0);
    STAGE2_A(a1, 64);
    STAGE2_B(b1, 64);

    const int NT = K / 64;
    for (int t = 0; t < NT; t++) {
        if (t < NT - 1)
            asm volatile("s_waitcnt vmcnt(6)" ::: "memory");
        else
            asm volatile("s_waitcnt vmcnt(0)" ::: "memory");
        __builtin_amdgcn_s_barrier();
        __builtin_amdgcn_sched_barrier(0);
        const bool more = t + 2 < NT;
        const int kn = (t + 2) * 64;

        short8 afr[4][2], bfr[4][2];
#pragma unroll
        for (int i = 0; i < 4; i++)
#pragma unroll
            for (int kq = 0; kq < 2; kq++)
                afr[i][kq] = RD2(a0, wr * 64 + i * 16 + lrow, kq * 4 + quad);
#pragma unroll
        for (int j = 0; j < 2; j++)
#pragma unroll
            for (int kq = 0; kq < 2; kq++)
                bfr[j][kq] = RD2(b0, wc * 64 + j * 16 + lrow, kq * 4 + quad);
        if (more) STAGE2_A(a2, kn);
        LGKM0();
        __builtin_amdgcn_s_setprio(1);
#pragma unroll
        for (int i = 0; i < 4; i++)
#pragma unroll
            for (int j = 0; j < 2; j++)
#pragma unroll
                for (int kq = 0; kq < 2; kq++)
                    acc[i][j] = __builtin_amdgcn_mfma_f32_16x16x32_bf16(
                        afr[i][kq], bfr[j][kq], acc[i][j], 0, 0, 0);
        __builtin_amdgcn_s_setprio(0);

#pragma unroll
        for (int j = 2; j < 4; j++)
#pragma unroll
            for (int kq = 0; kq < 2; kq++)
                bfr[j][kq] = RD2(b0, wc * 64 + j * 16 + lrow, kq * 4 + quad);
        if (more) STAGE2_B(b2, kn);
        LGKM0();
        __builtin_amdgcn_s_setprio(1);
#pragma unroll
        for (int i = 0; i < 4; i++)
#pragma unroll
            for (int j = 2; j < 4; j++)
#pragma unroll
                for (int kq = 0; kq < 2; kq++)
                    acc[i][j] = __builtin_amdgcn_mfma_f32_16x16x32_bf16(
                        afr[i][kq], bfr[j][kq], acc[i][j], 0, 0, 0);
        __builtin_amdgcn_s_setprio(0);

        short* ta = a0; a0 = a1; a1 = a2; a2 = ta;
        short* tb = b0; b0 = b1; b1 = b2; b2 = tb;
    }
#undef STAGE2_A
#undef STAGE2_B
#undef RD2
#undef LGKM0

#pragma unroll
    for (int i = 0; i < 4; i++)
#pragma unroll
        for (int j = 0; j < 4; j++) {
            int col = bn * 128 + wc * 64 + j * 16 + lrow;
            float bv = bias[col];
#pragma unroll
            for (int r = 0; r < 4; r++) {
                int row = bm * 256 + wr * 64 + i * 16 + quad * 4 + r;
                float v = acc[i][j][r] + bv + __bfloat162float(RES[(size_t)row * N + col]);
                Cout[(size_t)row * N + col] = v;
            }
        }
}

// ---------------- launch ----------------
extern "C" void kernel_launch(void* const* d_in, const int* in_sizes, int n_in,
                              void* d_out, int out_size, void* d_ws, size_t ws_size,
                              hipStream_t stream) {
    const float* x = (const float*)d_in[0];
    const float* w1 = (const float*)d_in[1];
    const float* b1 = (const float*)d_in[2];
    const float* w2 = (const float*)d_in[3];
    const float* b2 = (const float*)d_in[4];
    const float* g1 = (const float*)d_in[5];
    const float* be1 = (const float*)d_in[6];
    const float* g2 = (const float*)d_in[7];
    const float* be2 = (const float*)d_in[8];
    float* out = (float*)d_out;

    char* ws = (char*)d_ws;
    const size_t MB = 1024 * 1024;
    float* attn_out = (float*)(ws);            // 32 MiB
    bf16* x1b = (bf16*)(ws + 64 * MB);         // 16 MiB (LN1 out, bf16: gemm1 A + gemm2 RES)
    bf16* w1b = (bf16*)(ws + 80 * MB);         // 8 MiB
    bf16* w2b = (bf16*)(ws + 88 * MB);         // 8 MiB
    bf16* hb = (bf16*)(ws + 96 * MB);          // 64 MiB (GEMM phase)
    // attention-phase buffers alias hb's region (dead once gemm1 runs):
    short* xb = (short*)(ws + 96 * MB);        // 16 MiB bf16 x
    short* vt = (short*)(ws + 112 * MB);       // 16 MiB bf16 x^T per (b,h)
    float* y2 = attn_out;                      // reuse

    convert_bf16_kernel<<<4096, 256, 0, stream>>>(w1, w1b, F_ * D_);
    convert_bf16_kernel<<<4096, 256, 0, stream>>>(w2, w2b, D_ * F_);
    transpose_vt_kernel<<<dim3(B_ * H_, L_ / 64), 256, 0, stream>>>(x, vt, xb);

    flash_attn_kernel<<<B_ * H_ * (L_ / 128), 256, 0, stream>>>(x, xb, vt, attn_out);

    // LN1: bf16 out only (residual for gemm2 is read back as bf16)
    ln_kernel<<<B_ * L_, 256, 0, stream>>>(x, attn_out, g1, be1, nullptr, x1b);

    // gemm1: M=8192, N=4096, K=1024 -> 256x256 tiles, grid 16 x 32 = 512 wg
    gemm1_sq<<<dim3(F_ / 256, (B_ * L_) / 256), 512, 0, stream>>>(
        x1b, w1b, b1, hb, B_ * L_, F_, D_);
    // gemm2: M=8192, N=1024, K=4096 -> grid 8 x 32 = 256 wg, 3-deep pipeline
    gemm2_k<<<dim3(D_ / 128, (B_ * L_) / 256), 512, 0, stream>>>(
        hb, w2b, b2, x1b, y2, B_ * L_, D_, F_);

    ln_kernel<<<B_ * L_, 256, 0, stream>>>(y2, nullptr, g2, be2, out, nullptr);
}

// Round 13
// 242.291 us; speedup vs baseline: 1.0972x; 1.0322x over previous
//
#include <hip/hip_runtime.h>
#include <hip/hip_bf16.h>

#define B_ 4
#define L_ 2048
#define D_ 1024
#define F_ 4096
#define H_ 16
#define E_ 64

typedef __hip_bfloat16 bf16;
typedef __attribute__((ext_vector_type(8))) short short8;
typedef __attribute__((ext_vector_type(4))) float f32x4;
typedef __attribute__((ext_vector_type(16))) float f32x16;

__device__ __forceinline__ short f2bf(float f) {
    union { float f; unsigned u; } v;
    v.f = f;
    unsigned r = (v.u + 0x7fff + ((v.u >> 16) & 1)) >> 16;
    return (short)r;
}

// async global->LDS, 16B per lane, lands at ldsbase + lane*16
__device__ __forceinline__ void gl_lds16(const short* g, short* l) {
    __builtin_amdgcn_global_load_lds((const __attribute__((address_space(1))) void*)g,
                                     (__attribute__((address_space(3))) void*)l, 16, 0, 0);
}

// ---------------- fp32 -> bf16 convert ----------------
__global__ __launch_bounds__(256) void convert_bf16_kernel(const float* __restrict__ src,
                                                           bf16* __restrict__ dst, int n) {
    int i = (blockIdx.x * 256 + threadIdx.x) * 4;
    if (i + 3 < n) {
        float4 v = *(const float4*)(src + i);
        dst[i + 0] = __float2bfloat16(v.x);
        dst[i + 1] = __float2bfloat16(v.y);
        dst[i + 2] = __float2bfloat16(v.z);
        dst[i + 3] = __float2bfloat16(v.w);
    }
}

// ---------------- V^T pre-pass + bf16 x copy ----------------
__global__ __launch_bounds__(256) void transpose_vt_kernel(const float* __restrict__ x,
                                                           short* __restrict__ vt,
                                                           short* __restrict__ xb) {
    __shared__ float tile[64][65];
    const int bh = blockIdx.x, lt = blockIdx.y;
    const int b = bh >> 4, h = bh & 15;
    const int l0 = lt * 64;
    for (int idx = threadIdx.x; idx < 4096; idx += 256) {
        int r = idx >> 6, c = idx & 63;
        float v = x[((size_t)b * L_ + l0 + r) * D_ + h * E_ + c];
        tile[r][c] = v;
        xb[((size_t)b * L_ + l0 + r) * D_ + h * E_ + c] = f2bf(v);
    }
    __syncthreads();
    for (int idx = threadIdx.x; idx < 4096; idx += 256) {
        int e = idx >> 6, l = idx & 63;
        vt[((size_t)bh * E_ + e) * L_ + l0 + l] = f2bf(tile[l][e]);
    }
}

// ---------------- flash attention: 8 waves x 32 q-rows (QBLK=256), swapped 32x32 MFMA ----------------
// m214-verified block shape: 8 warps/QBLK=256 amortizes K/V staging over 2x compute
// (2 gl_lds issues/wave/tile instead of 4) and gives 8-wave barrier slack.
// grid 512; XCD-grouping swizzle (id&7 owns 8 heads = 4MB K/V = its L2).
// K/V in unpadded KV[2][2][64][64], row-half-invariant XOR swizzle (phys chunk = logical^(r&7),
// both-sides). l-sum = per-lane VALU, 2 chains. Double-buffered, one __syncthreads per tile.
__global__ __launch_bounds__(512, 4) void flash_attn_kernel(const float* __restrict__ x,
                                                            const short* __restrict__ xb,
                                                            const short* __restrict__ vt,
                                                            float* __restrict__ attn_out) {
    __shared__ short KV[2][2][64][64];   // [buf][K=0/V=1][row][chunk*8]

    const int tid = threadIdx.x;
    const int w = tid >> 6, lane = tid & 63;   // w in 0..7
    const int l31 = lane & 31;
    const int hi = lane >> 5;
    const int hi8 = hi * 8;

    // XCD-grouping bijection: blocks of one (b,h) stay on one XCD
    const int orig = blockIdx.x;
    const int xcd = orig & 7;
    const int seq = orig >> 3;        // 0..63
    const int qt = seq & 7;           // 8 q-tiles of 256
    const int bh = ((seq >> 3) << 3) | xcd;
    const int b = bh >> 4, h = bh & 15;
    const int q0 = qt * 256;

    const short* kbase = xb + (size_t)b * L_ * D_ + h * E_;

    const float QS = 0.125f * 1.44269504f;
    const int qrow = q0 + w * 32 + l31;
    short8 qf[4];
    {
        const float* qp = x + ((size_t)b * L_ + qrow) * D_ + h * E_;
#pragma unroll
        for (int ks = 0; ks < 4; ks++) {
            float4 v0 = *(const float4*)(qp + ks * 16 + hi8);
            float4 v1 = *(const float4*)(qp + ks * 16 + hi8 + 4);
            short8 sc;
            sc[0] = f2bf(v0.x * QS); sc[1] = f2bf(v0.y * QS);
            sc[2] = f2bf(v0.z * QS); sc[3] = f2bf(v0.w * QS);
            sc[4] = f2bf(v1.x * QS); sc[5] = f2bf(v1.y * QS);
            sc[6] = f2bf(v1.z * QS); sc[7] = f2bf(v1.w * QS);
            qf[ks] = sc;
        }
    }

    f32x16 acc_o[2];
    float lsum0 = 0.f, lsum1 = 0.f;
#pragma unroll
    for (int r = 0; r < 16; r++) { acc_o[0][r] = 0.f; acc_o[1][r] = 0.f; }

    // staging: wave w covers K rows [w*8, w*8+8) and V rows [w*8, w*8+8); 2 issues/wave.
    // source chunk pre-permuted: phys chunk (lane&7) at row r holds logical (lane&7)^(r&7).
    const int srow = lane >> 3;                       // 0..7 within 8-row issue
    const int schunk = ((lane & 7) ^ srow) * 8;       // logical chunk this lane fetches
    const short* ksrc0 = kbase + (size_t)(w * 8 + srow) * D_ + schunk;
    const short* vsrc0 = vt + ((size_t)bh * E_ + w * 8 + srow) * L_ + schunk;

#define STAGEF(bf_, t_)                                                 \
    do {                                                                \
        gl_lds16(ksrc0 + (size_t)(t_) * 64 * D_, &KV[bf_][0][w * 8][0]);\
        gl_lds16(vsrc0 + (size_t)(t_) * 64, &KV[bf_][1][w * 8][0]);     \
    } while (0)

    // per-lane read base: phys chunk of logical chunk (hi) at row l31; valid for rows
    // l31 and 32+l31 alike since the swizzle term is (r&7).
    const int p0 = l31 * 128 + ((((l31 & 7) ^ hi)) << 4);

    STAGEF(0, 0);   // prefetch tile 0

    const int NT = L_ / 64;
    for (int t = 0; t < NT; t++) {
        const int cur = t & 1;
        __syncthreads();   // drains vmcnt(0): tile t landed; all prior reads done

        if (t + 1 < NT) STAGEF(cur ^ 1, t + 1);   // covered by the compute below

        const char* kvb = (const char*)&KV[cur][0][0][0];

        f32x16 accp0, accp1;
#pragma unroll
        for (int r = 0; r < 16; r++) { accp0[r] = 0.f; accp1[r] = 0.f; }
        __builtin_amdgcn_s_setprio(1);
#pragma unroll
        for (int j = 0; j < 4; j++) {
            short8 kf0 = *(const short8*)(kvb + (p0 ^ (j << 5)));
            short8 kf1 = *(const short8*)(kvb + 4096 + (p0 ^ (j << 5)));
            accp0 = __builtin_amdgcn_mfma_f32_32x32x16_bf16(kf0, qf[j], accp0, 0, 0, 0);
            accp1 = __builtin_amdgcn_mfma_f32_32x32x16_bf16(kf1, qf[j], accp1, 0, 0, 0);
        }
        __builtin_amdgcn_s_setprio(0);

        float pe[2][16];
#pragma unroll
        for (int r = 0; r < 16; r++) {
            pe[0][r] = __builtin_amdgcn_exp2f(accp0[r]);
            pe[1][r] = __builtin_amdgcn_exp2f(accp1[r]);
        }
        // per-lane l partials (two independent chains)
#pragma unroll
        for (int r = 0; r < 16; r++) { lsum0 += pe[0][r]; lsum1 += pe[1][r]; }

#pragma unroll
        for (int j = 0; j < 4; j++) {
            const int tt = j >> 1, o = (j & 1) * 8;
            unsigned X0, X1, Y0, Y1;
            asm("v_cvt_pk_bf16_f32 %0, %1, %2" : "=v"(X0) : "v"(pe[tt][o + 0]), "v"(pe[tt][o + 1]));
            asm("v_cvt_pk_bf16_f32 %0, %1, %2" : "=v"(X1) : "v"(pe[tt][o + 2]), "v"(pe[tt][o + 3]));
            asm("v_cvt_pk_bf16_f32 %0, %1, %2" : "=v"(Y0) : "v"(pe[tt][o + 4]), "v"(pe[tt][o + 5]));
            asm("v_cvt_pk_bf16_f32 %0, %1, %2" : "=v"(Y1) : "v"(pe[tt][o + 6]), "v"(pe[tt][o + 7]));
            asm("v_permlane32_swap_b32 %0, %1" : "+v"(X0), "+v"(Y0));
            asm("v_permlane32_swap_b32 %0, %1" : "+v"(X1), "+v"(Y1));
            int4 wi = make_int4((int)X0, (int)X1, (int)Y0, (int)Y1);
            short8 pb = *(short8*)&wi;

            __builtin_amdgcn_s_setprio(1);
            short8 vf0 = *(const short8*)(kvb + 8192 + (p0 ^ (j << 5)));
            short8 vf1 = *(const short8*)(kvb + 12288 + (p0 ^ (j << 5)));
            acc_o[0] = __builtin_amdgcn_mfma_f32_32x32x16_bf16(vf0, pb, acc_o[0], 0, 0, 0);
            acc_o[1] = __builtin_amdgcn_mfma_f32_32x32x16_bf16(vf1, pb, acc_o[1], 0, 0, 0);
            __builtin_amdgcn_s_setprio(0);
        }
    }
#undef STAGEF

    // epilogue: O /= l.  l = own partial + hi-partner partial (same q column).
    const float lsum = lsum0 + lsum1;
    const float ltot = lsum + __shfl_xor(lsum, 32, 64);
    const float il = 1.0f / ltot;
    float* op = attn_out + ((size_t)b * L_ + qrow) * D_ + h * E_ + hi * 4;
#pragma unroll
    for (int et = 0; et < 2; et++)
#pragma unroll
        for (int rg = 0; rg < 4; rg++) {
            float4 ov;
            ov.x = acc_o[et][rg * 4 + 0] * il;
            ov.y = acc_o[et][rg * 4 + 1] * il;
            ov.z = acc_o[et][rg * 4 + 2] * il;
            ov.w = acc_o[et][rg * 4 + 3] * il;
            *(float4*)(op + et * 32 + rg * 8) = ov;
        }
}

// ---------------- residual + layernorm (f32 inputs), optional second input ----------------
__global__ __launch_bounds__(256) void ln_kernel(const float* __restrict__ A,
                                                 const float* __restrict__ Bres,
                                                 const float* __restrict__ gamma,
                                                 const float* __restrict__ beta,
                                                 float* __restrict__ out_f32,
                                                 bf16* __restrict__ out_bf16) {
    __shared__ float reds[4], reds2[4];
    const int row = blockIdx.x, tid = threadIdx.x;
    const int c4 = tid * 4;
    float4 va = *(const float4*)(A + (size_t)row * D_ + c4);
    if (Bres) {
        float4 vb = *(const float4*)(Bres + (size_t)row * D_ + c4);
        va.x += vb.x; va.y += vb.y; va.z += vb.z; va.w += vb.w;
    }
    float s = va.x + va.y + va.z + va.w;
    float s2 = va.x * va.x + va.y * va.y + va.z * va.z + va.w * va.w;
#pragma unroll
    for (int o = 32; o > 0; o >>= 1) {
        s += __shfl_down(s, o, 64);
        s2 += __shfl_down(s2, o, 64);
    }
    if ((tid & 63) == 0) { reds[tid >> 6] = s; reds2[tid >> 6] = s2; }
    __syncthreads();
    s = reds[0] + reds[1] + reds[2] + reds[3];
    s2 = reds2[0] + reds2[1] + reds2[2] + reds2[3];
    float mean = s * (1.0f / D_);
    float var = s2 * (1.0f / D_) - mean * mean;
    float r = rsqrtf(var + 1e-5f);
    float4 vg = *(const float4*)(gamma + c4);
    float4 vbt = *(const float4*)(beta + c4);
    float4 o;
    o.x = (va.x - mean) * r * vg.x + vbt.x;
    o.y = (va.y - mean) * r * vg.y + vbt.y;
    o.z = (va.z - mean) * r * vg.z + vbt.z;
    o.w = (va.w - mean) * r * vg.w + vbt.w;
    if (out_f32) *(float4*)(out_f32 + (size_t)row * D_ + c4) = o;
    if (out_bf16) {
        unsigned p0 = ((unsigned)(unsigned short)f2bf(o.x)) | (((unsigned)(unsigned short)f2bf(o.y)) << 16);
        unsigned p1 = ((unsigned)(unsigned short)f2bf(o.z)) | (((unsigned)(unsigned short)f2bf(o.w)) << 16);
        int2 pk = make_int2((int)p0, (int)p1);
        *(int2*)((short*)out_bf16 + (size_t)row * D_ + c4) = pk;
    }
}

// ---------------- layernorm with bf16 input (final LN; halves the read traffic) ----------------
__global__ __launch_bounds__(256) void ln_bf16_kernel(const bf16* __restrict__ A,
                                                      const float* __restrict__ gamma,
                                                      const float* __restrict__ beta,
                                                      float* __restrict__ out_f32) {
    __shared__ float reds[4], reds2[4];
    const int row = blockIdx.x, tid = threadIdx.x;
    const int c4 = tid * 4;
    int2 pk = *(const int2*)((const short*)A + (size_t)row * D_ + c4);
    float4 va;
    va.x = __uint_as_float(((unsigned)pk.x & 0xffffu) << 16);
    va.y = __uint_as_float((unsigned)pk.x & 0xffff0000u);
    va.z = __uint_as_float(((unsigned)pk.y & 0xffffu) << 16);
    va.w = __uint_as_float((unsigned)pk.y & 0xffff0000u);
    float s = va.x + va.y + va.z + va.w;
    float s2 = va.x * va.x + va.y * va.y + va.z * va.z + va.w * va.w;
#pragma unroll
    for (int o = 32; o > 0; o >>= 1) {
        s += __shfl_down(s, o, 64);
        s2 += __shfl_down(s2, o, 64);
    }
    if ((tid & 63) == 0) { reds[tid >> 6] = s; reds2[tid >> 6] = s2; }
    __syncthreads();
    s = reds[0] + reds[1] + reds[2] + reds[3];
    s2 = reds2[0] + reds2[1] + reds2[2] + reds2[3];
    float mean = s * (1.0f / D_);
    float var = s2 * (1.0f / D_) - mean * mean;
    float r = rsqrtf(var + 1e-5f);
    float4 vg = *(const float4*)(gamma + c4);
    float4 vbt = *(const float4*)(beta + c4);
    float4 o;
    o.x = (va.x - mean) * r * vg.x + vbt.x;
    o.y = (va.y - mean) * r * vg.y + vbt.y;
    o.z = (va.z - mean) * r * vg.z + vbt.z;
    o.w = (va.w - mean) * r * vg.w + vbt.w;
    *(float4*)(out_f32 + (size_t)row * D_ + c4) = o;
}

// ---------------- gemm1: 256x256 tile, 8 waves 2Mx4N, 2-deep bufs, barrier-drain pipeline ----------------
__global__ __launch_bounds__(512, 1) void gemm1_sq(const bf16* __restrict__ A,
                                                   const bf16* __restrict__ Bw,
                                                   const float* __restrict__ bias,
                                                   bf16* __restrict__ Cout,
                                                   int M, int N, int K) {
    __shared__ short As[2][256 * 64];
    __shared__ short Bs[2][256 * 64];

    const int tid = threadIdx.x;
    const int wid = tid >> 6, lane = tid & 63;
    const int wr = wid >> 2, wc = wid & 3;       // 2M x 4N waves, 128x64 out each
    const int lrow = lane & 15, quad = lane >> 4;

    // T1 bijective XCD swizzle (grid = 16 x 32 = 512 wg, %8==0)
    const int nbx = gridDim.x;
    const int id = blockIdx.y * nbx + blockIdx.x;
    const int chunk = (nbx * gridDim.y) >> 3;
    const int swz = (id & 7) * chunk + (id >> 3);
    const int bn = swz % nbx, bm = swz / nbx;

    const int srow = wid * 32 + (lane >> 3);
    const int scol = ((lane & 7) ^ ((lane >> 3) & 7)) * 8;
    const short* Ag = (const short*)A + (size_t)(bm * 256 + srow) * K + scol;
    const short* Bg = (const short*)Bw + (size_t)(bn * 256 + srow) * K + scol;

    f32x4 acc[8][4];
#pragma unroll
    for (int i = 0; i < 8; i++)
#pragma unroll
        for (int j = 0; j < 4; j++) acc[i][j] = (f32x4){0.f, 0.f, 0.f, 0.f};

#define SQ_STAGE_A(b, k0)                                                              \
    do {                                                                               \
        _Pragma("unroll") for (int s = 0; s < 4; s++)                                  \
            gl_lds16(Ag + (size_t)s * 8 * K + (k0), &As[b][(wid * 32 + s * 8) * 64]);  \
    } while (0)
#define SQ_STAGE_B(b, k0)                                                              \
    do {                                                                               \
        _Pragma("unroll") for (int s = 0; s < 4; s++)                                  \
            gl_lds16(Bg + (size_t)s * 8 * K + (k0), &Bs[b][(wid * 32 + s * 8) * 64]);  \
    } while (0)
#define SQ_RD(base, R, q) (*(const short8*)&(base)[(R) * 64 + (((q) ^ ((R) & 7)) * 8)])
#define LGKM0()                                            \
    do {                                                   \
        asm volatile("s_waitcnt lgkmcnt(0)" ::: "memory"); \
        __builtin_amdgcn_sched_barrier(0);                 \
    } while (0)

    SQ_STAGE_A(0, 0);
    SQ_STAGE_B(0, 0);

    const int NT = K / 64;
    for (int t = 0; t < NT; t++) {
        const int cur = t & 1;
        __syncthreads();
        const bool more = t + 1 < NT;
        const int kn = (t + 1) * 64;

        short8 af[4][2], bfr[4][2];
#pragma unroll
        for (int i = 0; i < 4; i++)
#pragma unroll
            for (int kq = 0; kq < 2; kq++)
                af[i][kq] = SQ_RD(As[cur], wr * 128 + i * 16 + lrow, kq * 4 + quad);
#pragma unroll
        for (int j = 0; j < 4; j++)
#pragma unroll
            for (int kq = 0; kq < 2; kq++)
                bfr[j][kq] = SQ_RD(Bs[cur], wc * 64 + j * 16 + lrow, kq * 4 + quad);
        if (more) SQ_STAGE_A(cur ^ 1, kn);
        LGKM0();
        __builtin_amdgcn_s_setprio(1);
#pragma unroll
        for (int i = 0; i < 4; i++)
#pragma unroll
            for (int j = 0; j < 4; j++)
#pragma unroll
                for (int kq = 0; kq < 2; kq++)
                    acc[i][j] = __builtin_amdgcn_mfma_f32_16x16x32_bf16(
                        af[i][kq], bfr[j][kq], acc[i][j], 0, 0, 0);
        __builtin_amdgcn_s_setprio(0);

#pragma unroll
        for (int i = 0; i < 4; i++)
#pragma unroll
            for (int kq = 0; kq < 2; kq++)
                af[i][kq] = SQ_RD(As[cur], wr * 128 + 64 + i * 16 + lrow, kq * 4 + quad);
        if (more) SQ_STAGE_B(cur ^ 1, kn);
        LGKM0();
        __builtin_amdgcn_s_setprio(1);
#pragma unroll
        for (int i = 0; i < 4; i++)
#pragma unroll
            for (int j = 0; j < 4; j++)
#pragma unroll
                for (int kq = 0; kq < 2; kq++)
                    acc[4 + i][j] = __builtin_amdgcn_mfma_f32_16x16x32_bf16(
                        af[i][kq], bfr[j][kq], acc[4 + i][j], 0, 0, 0);
        __builtin_amdgcn_s_setprio(0);
    }
#undef SQ_STAGE_A
#undef SQ_STAGE_B
#undef SQ_RD
#undef LGKM0

    // epilogue: relu -> bf16
#pragma unroll
    for (int i = 0; i < 8; i++)
#pragma unroll
        for (int j = 0; j < 4; j++) {
            int col = bn * 256 + wc * 64 + j * 16 + lrow;
            float bv = bias[col];
#pragma unroll
            for (int r = 0; r < 4; r++) {
                int row = bm * 256 + wr * 128 + i * 16 + quad * 4 + r;
                float v = fmaxf(acc[i][j][r] + bv, 0.f);
                Cout[(size_t)row * N + col] = __float2bfloat16(v);
            }
        }
}

// ---------------- gemm2: 256x128 tile, 8 waves 4Mx2N, 3-deep buffers, counted vmcnt ----------------
// bf16 out (y2 narrow path) + bf16 residual RES.
__global__ __launch_bounds__(512, 1) void gemm2_k(const bf16* __restrict__ A,
                                                  const bf16* __restrict__ Bw,
                                                  const float* __restrict__ bias,
                                                  const bf16* __restrict__ RES,
                                                  bf16* __restrict__ Cout,
                                                  int M, int N, int K) {
    __shared__ short As[3][256 * 64];
    __shared__ short Bs[3][128 * 64];

    const int tid = threadIdx.x;
    const int wid = tid >> 6, lane = tid & 63;
    const int wr = wid >> 1, wc = wid & 1;       // 4M x 2N waves, 64x64 out each
    const int lrow = lane & 15, quad = lane >> 4;

    const int nbx = gridDim.x;
    const int id = blockIdx.y * nbx + blockIdx.x;
    const int chunk = (nbx * gridDim.y) >> 3;
    const int swz = (id & 7) * chunk + (id >> 3);
    const int bn = swz % nbx, bm = swz / nbx;

    const int srow = wid * 8 + (lane >> 3);
    const int scol = ((lane & 7) ^ ((lane >> 3) & 7)) * 8;   // pre-permuted source (T2)
    const short* Ag = (const short*)A + (size_t)(bm * 256 + srow) * K + scol;
    const short* Bg = (const short*)Bw + (size_t)(bn * 128 + srow) * K + scol;

    f32x4 acc[4][4];
#pragma unroll
    for (int i = 0; i < 4; i++)
#pragma unroll
        for (int j = 0; j < 4; j++) acc[i][j] = (f32x4){0.f, 0.f, 0.f, 0.f};

#define STAGE2_A(dst, k0)                                                            \
    do {                                                                             \
        _Pragma("unroll") for (int s = 0; s < 4; s++)                                \
            gl_lds16(Ag + (size_t)s * 64 * K + (k0), (dst) + (s * 64 + wid * 8) * 64); \
    } while (0)
#define STAGE2_B(dst, k0)                                                            \
    do {                                                                             \
        _Pragma("unroll") for (int s = 0; s < 2; s++)                                \
            gl_lds16(Bg + (size_t)s * 64 * K + (k0), (dst) + (s * 64 + wid * 8) * 64); \
    } while (0)
#define RD2(base, R, q) (*(const short8*)&(base)[(R) * 64 + (((q) ^ ((R) & 7)) * 8)])
#define LGKM0()                                            \
    do {                                                   \
        asm volatile("s_waitcnt lgkmcnt(0)" ::: "memory"); \
        __builtin_amdgcn_sched_barrier(0);                 \
    } while (0)

    short* a0 = &As[0][0];
    short* a1 = &As[1][0];
    short* a2 = &As[2][0];
    short* b0 = &Bs[0][0];
    short* b1 = &Bs[1][0];
    short* b2 = &Bs[2][0];

    STAGE2_A(a0, 0);
    STAGE2_B(b0, 0);
    STAGE2_A(a1, 64);
    STAGE2_B(b1, 64);

    const int NT = K / 64;
    for (int t = 0; t < NT; t++) {
        if (t < NT - 1)
            asm volatile("s_waitcnt vmcnt(6)" ::: "memory");
        else
            asm volatile("s_waitcnt vmcnt(0)" ::: "memory");
        __builtin_amdgcn_s_barrier();
        __builtin_amdgcn_sched_barrier(0);
        const bool more = t + 2 < NT;
        const int kn = (t + 2) * 64;

        short8 afr[4][2], bfr[4][2];
#pragma unroll
        for (int i = 0; i < 4; i++)
#pragma unroll
            for (int kq = 0; kq < 2; kq++)
                afr[i][kq] = RD2(a0, wr * 64 + i * 16 + lrow, kq * 4 + quad);
#pragma unroll
        for (int j = 0; j < 2; j++)
#pragma unroll
            for (int kq = 0; kq < 2; kq++)
                bfr[j][kq] = RD2(b0, wc * 64 + j * 16 + lrow, kq * 4 + quad);
        if (more) STAGE2_A(a2, kn);
        LGKM0();
        __builtin_amdgcn_s_setprio(1);
#pragma unroll
        for (int i = 0; i < 4; i++)
#pragma unroll
            for (int j = 0; j < 2; j++)
#pragma unroll
                for (int kq = 0; kq < 2; kq++)
                    acc[i][j] = __builtin_amdgcn_mfma_f32_16x16x32_bf16(
                        afr[i][kq], bfr[j][kq], acc[i][j], 0, 0, 0);
        __builtin_amdgcn_s_setprio(0);

#pragma unroll
        for (int j = 2; j < 4; j++)
#pragma unroll
            for (int kq = 0; kq < 2; kq++)
                bfr[j][kq] = RD2(b0, wc * 64 + j * 16 + lrow, kq * 4 + quad);
        if (more) STAGE2_B(b2, kn);
        LGKM0();
        __builtin_amdgcn_s_setprio(1);
#pragma unroll
        for (int i = 0; i < 4; i++)
#pragma unroll
            for (int j = 2; j < 4; j++)
#pragma unroll
                for (int kq = 0; kq < 2; kq++)
                    acc[i][j] = __builtin_amdgcn_mfma_f32_16x16x32_bf16(
                        afr[i][kq], bfr[j][kq], acc[i][j], 0, 0, 0);
        __builtin_amdgcn_s_setprio(0);

        short* ta = a0; a0 = a1; a1 = a2; a2 = ta;
        short* tb = b0; b0 = b1; b1 = b2; b2 = tb;
    }
#undef STAGE2_A
#undef STAGE2_B
#undef RD2
#undef LGKM0

#pragma unroll
    for (int i = 0; i < 4; i++)
#pragma unroll
        for (int j = 0; j < 4; j++) {
            int col = bn * 128 + wc * 64 + j * 16 + lrow;
            float bv = bias[col];
#pragma unroll
            for (int r = 0; r < 4; r++) {
                int row = bm * 256 + wr * 64 + i * 16 + quad * 4 + r;
                float v = acc[i][j][r] + bv + __bfloat162float(RES[(size_t)row * N + col]);
                Cout[(size_t)row * N + col] = __float2bfloat16(v);
            }
        }
}

// ---------------- launch ----------------
extern "C" void kernel_launch(void* const* d_in, const int* in_sizes, int n_in,
                              void* d_out, int out_size, void* d_ws, size_t ws_size,
                              hipStream_t stream) {
    const float* x = (const float*)d_in[0];
    const float* w1 = (const float*)d_in[1];
    const float* b1 = (const float*)d_in[2];
    const float* w2 = (const float*)d_in[3];
    const float* b2 = (const float*)d_in[4];
    const float* g1 = (const float*)d_in[5];
    const float* be1 = (const float*)d_in[6];
    const float* g2 = (const float*)d_in[7];
    const float* be2 = (const float*)d_in[8];
    float* out = (float*)d_out;

    char* ws = (char*)d_ws;
    const size_t MB = 1024 * 1024;
    float* attn_out = (float*)(ws);            // 32 MiB (attention phase)
    bf16* y2b = (bf16*)(ws);                   // 16 MiB (reuses attn_out region after LN1)
    bf16* x1b = (bf16*)(ws + 64 * MB);         // 16 MiB (LN1 out: gemm1 A + gemm2 RES)
    bf16* w1b = (bf16*)(ws + 80 * MB);         // 8 MiB
    bf16* w2b = (bf16*)(ws + 88 * MB);         // 8 MiB
    bf16* hb = (bf16*)(ws + 96 * MB);          // 64 MiB (GEMM phase)
    // attention-phase buffers alias hb's region (dead once gemm1 runs):
    short* xb = (short*)(ws + 96 * MB);        // 16 MiB bf16 x
    short* vt = (short*)(ws + 112 * MB);       // 16 MiB bf16 x^T per (b,h)

    convert_bf16_kernel<<<4096, 256, 0, stream>>>(w1, w1b, F_ * D_);
    convert_bf16_kernel<<<4096, 256, 0, stream>>>(w2, w2b, D_ * F_);
    transpose_vt_kernel<<<dim3(B_ * H_, L_ / 64), 256, 0, stream>>>(x, vt, xb);

    // flash: 8 waves x 32 q-rows (QBLK=256) -> grid 512
    flash_attn_kernel<<<B_ * H_ * (L_ / 256), 512, 0, stream>>>(x, xb, vt, attn_out);

    // LN1: bf16 out only (residual for gemm2 is read back as bf16)
    ln_kernel<<<B_ * L_, 256, 0, stream>>>(x, attn_out, g1, be1, nullptr, x1b);

    // gemm1: M=8192, N=4096, K=1024 -> 256x256 tiles, grid 16 x 32 = 512 wg
    gemm1_sq<<<dim3(F_ / 256, (B_ * L_) / 256), 512, 0, stream>>>(
        x1b, w1b, b1, hb, B_ * L_, F_, D_);
    // gemm2: M=8192, N=1024, K=4096 -> grid 8 x 32 = 256 wg, bf16 out
    gemm2_k<<<dim3(D_ / 128, (B_ * L_) / 256), 512, 0, stream>>>(
        hb, w2b, b2, x1b, y2b, B_ * L_, D_, F_);

    // LN2: bf16 in -> f32 out
    ln_bf16_kernel<<<B_ * L_, 256, 0, stream>>>(y2b, g2, be2, out);
}